// Round 3
// baseline (224.619 us; speedup 1.0000x reference)
//
#include <hip/hip_runtime.h>

typedef __attribute__((ext_vector_type(8))) _Float16 h8;
typedef __attribute__((ext_vector_type(4))) float f4;

#define QKSCALE 0.18033688011112042f  // 2^-3 * log2(e): fold softmax scale + exp2 conversion into Q

// ---------------- cast x (fp32 -> f16) ----------------
__global__ __launch_bounds__(256) void cast_f16_kernel(const float* __restrict__ in,
                                                       _Float16* __restrict__ out, int n) {
  int i = (blockIdx.x * 256 + threadIdx.x) * 8;
  if (i >= n) return;
  const float4* p = (const float4*)(in + i);
  float4 a = p[0], b = p[1];
  h8 v;
  v[0] = (_Float16)a.x; v[1] = (_Float16)a.y; v[2] = (_Float16)a.z; v[3] = (_Float16)a.w;
  v[4] = (_Float16)b.x; v[5] = (_Float16)b.y; v[6] = (_Float16)b.z; v[7] = (_Float16)b.w;
  *(h8*)(out + i) = v;
}

// ---------------- transpose-cast W [K][N] fp32 -> Wt [N][K] f16 ----------------
__global__ __launch_bounds__(256) void transp_cast_kernel(const float* __restrict__ W,
                                                          _Float16* __restrict__ Wt, int K, int N) {
  __shared__ _Float16 tile[64][72];
  int k0 = blockIdx.y * 64, n0 = blockIdx.x * 64;
  int t = threadIdx.x;
#pragma unroll
  for (int i = 0; i < 16; ++i) {
    int idx = i * 256 + t;
    int kr = idx >> 6, nc = idx & 63;
    tile[kr][nc] = (_Float16)W[(size_t)(k0 + kr) * N + n0 + nc];
  }
  __syncthreads();
#pragma unroll
  for (int i = 0; i < 2; ++i) {
    int idx = i * 256 + t;
    int nr = idx >> 3, kc = (idx & 7) * 8;
    h8 v;
#pragma unroll
    for (int j = 0; j < 8; ++j) v[j] = tile[kc + j][nr];
    *(h8*)&Wt[(size_t)(n0 + nr) * K + k0 + kc] = v;
  }
}

// ---------------- GEMM: C[M,N] = A[M,K] * Bt[N,K]^T (+bias), f16 MFMA ----------------
// MODE 0: outF fp32 row-major.  MODE 1: QKV scatter -> Q[B,H,T,D]*QKSCALE, K[B,H,T,D], V^T[B,H,D,T]
template <int MODE>
__global__ __launch_bounds__(256) void gemm_f16(const _Float16* __restrict__ A,
                                                const _Float16* __restrict__ Bt,
                                                const float* __restrict__ bias,
                                                float* __restrict__ outF,
                                                _Float16* __restrict__ oQ,
                                                _Float16* __restrict__ oK,
                                                _Float16* __restrict__ oV,
                                                int M, int N, int K) {
  __shared__ _Float16 As[128 * 64];
  __shared__ _Float16 Bs[128 * 64];
  const int m0 = blockIdx.y * 128, n0 = blockIdx.x * 128;
  const int tid = threadIdx.x;
  const int wave = tid >> 6, lane = tid & 63;
  const int wr = (wave >> 1) * 64, wc = (wave & 1) * 64;
  const int lrow = lane & 15, g = lane >> 4;
  f4 acc[4][4];
  const f4 z4 = {0.f, 0.f, 0.f, 0.f};
#pragma unroll
  for (int m = 0; m < 4; ++m)
#pragma unroll
    for (int n = 0; n < 4; ++n) acc[m][n] = z4;

  for (int k0 = 0; k0 < K; k0 += 64) {
    // stage A/B tiles [128 rows][64 k] with XOR chunk swizzle (chunk = 16B)
#pragma unroll
    for (int i = 0; i < 4; ++i) {
      int L = i * 256 + tid;
      int row = L >> 3, c = L & 7;
      int cs = (c ^ (row & 7)) * 8;
      *(h8*)&As[row * 64 + c * 8] = *(const h8*)&A[(size_t)(m0 + row) * K + k0 + cs];
      *(h8*)&Bs[row * 64 + c * 8] = *(const h8*)&Bt[(size_t)(n0 + row) * K + k0 + cs];
    }
    __syncthreads();
#pragma unroll
    for (int ss = 0; ss < 2; ++ss) {
      h8 af[4], bf[4];
#pragma unroll
      for (int m = 0; m < 4; ++m) {
        int row = wr + m * 16 + lrow;
        af[m] = *(const h8*)&As[row * 64 + (((ss * 4 + g) ^ (row & 7)) * 8)];
      }
#pragma unroll
      for (int n = 0; n < 4; ++n) {
        int row = wc + n * 16 + lrow;
        bf[n] = *(const h8*)&Bs[row * 64 + (((ss * 4 + g) ^ (row & 7)) * 8)];
      }
#pragma unroll
      for (int m = 0; m < 4; ++m)
#pragma unroll
        for (int n = 0; n < 4; ++n)
          acc[m][n] = __builtin_amdgcn_mfma_f32_16x16x32_f16(af[m], bf[n], acc[m][n], 0, 0, 0);
    }
    __syncthreads();
  }

  // epilogue; C/D layout: col = lane&15, row = (lane>>4)*4 + r  [m89]
#pragma unroll
  for (int n = 0; n < 4; ++n) {
    const int gcol = n0 + wc + n * 16 + lrow;
    const float bv = bias ? bias[gcol] : 0.f;
#pragma unroll
    for (int m = 0; m < 4; ++m) {
#pragma unroll
      for (int r = 0; r < 4; ++r) {
        const int grow = m0 + wr + m * 16 + g * 4 + r;
        float v = acc[m][n][r] + bv;
        if (MODE == 0) {
          outF[(size_t)grow * N + gcol] = v;
        } else {
          int part = gcol >> 10;
          int c1 = gcol & 1023;
          int hh = c1 >> 6, d = c1 & 63;
          int b = grow >> 11, t = grow & 2047;
          int bh = b * 16 + hh;
          if (part == 0)
            oQ[((size_t)bh * 2048 + t) * 64 + d] = (_Float16)(v * QKSCALE);
          else if (part == 1)
            oK[((size_t)bh * 2048 + t) * 64 + d] = (_Float16)v;
          else
            oV[((size_t)bh * 64 + d) * 2048 + t] = (_Float16)v;
        }
      }
    }
  }
}

// ---------------- flash attention v3: split-KV, low-LDS, defer-max, lazy l-reduce --------
// Block = 32 q-rows. 4 waves split KV tiles (it = wave, wave+4, ...), merge at end.
// slab[wave] is P staging during the loop, then reused for NORMALIZED (o/l) f16
// O partials (wave-private -> safe alias). l kept as per-lane partials, reduced
// once after the loop. Defer-max (THR=8) skips row-max shfls + rescale in the
// common case, so fast-path iterations have zero cross-lane ops.
__global__ __launch_bounds__(256, 4) void attn_kernel(const _Float16* __restrict__ Qg,
                                                      const _Float16* __restrict__ Kg,
                                                      const _Float16* __restrict__ Vtg,
                                                      _Float16* __restrict__ Og) {
  __shared__ _Float16 slab[4][32][72];  // P staging -> normalized O partials (f16)
  __shared__ float mlds[2][4][32];      // [0]=m, [1]=l per wave per q-row

  const int idx = blockIdx.x;
  // XCD-affinity (%8 round-robin) + longest-first (high qt2 dispatched first)
  const int bh = (idx & 7) | (((idx >> 3) & 3) << 3);
  const int qt2 = 63 - (idx >> 5);
  const int q0 = qt2 * 32;

  const int wave = threadIdx.x >> 6, lane = threadIdx.x & 63;
  const int lrow = lane & 15, g = lane >> 4;
  const int b = bh >> 4, h = bh & 15;
  const _Float16* Q = Qg + (size_t)bh * 2048 * 64;
  const _Float16* K = Kg + (size_t)bh * 2048 * 64;
  const _Float16* Vt = Vtg + (size_t)bh * 64 * 2048;

  h8 aq[2][2];
#pragma unroll
  for (int mt = 0; mt < 2; ++mt)
#pragma unroll
    for (int ss = 0; ss < 2; ++ss)
      aq[mt][ss] = *(const h8*)&Q[(q0 + mt * 16 + lrow) * 64 + ss * 32 + g * 8];

  const f4 z4 = {0.f, 0.f, 0.f, 0.f};
  f4 o[2][4];
#pragma unroll
  for (int mt = 0; mt < 2; ++mt)
#pragma unroll
    for (int dt = 0; dt < 4; ++dt) o[mt][dt] = z4;
  float mrow[2][4], lpart[2][4];
#pragma unroll
  for (int mt = 0; mt < 2; ++mt)
#pragma unroll
    for (int r = 0; r < 4; ++r) { mrow[mt][r] = -1e30f; lpart[mt][r] = 0.f; }

  _Float16(*pw)[72] = slab[wave];
  const int NT = (qt2 >> 1) + 1;  // KV tiles of 64 covering rows [q0, q0+32)

  for (int it = wave; it < NT; it += 4) {
    const int kv0 = it * 64;
    // issue ALL K and V fragment loads up front (V overlaps QK+softmax)
    h8 kf[4][2], vf[4][2];
#pragma unroll
    for (int ct = 0; ct < 4; ++ct)
#pragma unroll
      for (int ss = 0; ss < 2; ++ss)
        kf[ct][ss] = *(const h8*)&K[(kv0 + ct * 16 + lrow) * 64 + ss * 32 + g * 8];
#pragma unroll
    for (int dt = 0; dt < 4; ++dt)
#pragma unroll
      for (int ss = 0; ss < 2; ++ss)
        vf[dt][ss] = *(const h8*)&Vt[(size_t)(dt * 16 + lrow) * 2048 + kv0 + ss * 32 + g * 8];

    f4 s[2][4];
#pragma unroll
    for (int mt = 0; mt < 2; ++mt)
#pragma unroll
      for (int ct = 0; ct < 4; ++ct) s[mt][ct] = z4;
#pragma unroll
    for (int ss = 0; ss < 2; ++ss)
#pragma unroll
      for (int mt = 0; mt < 2; ++mt)
#pragma unroll
        for (int ct = 0; ct < 4; ++ct)
          s[mt][ct] = __builtin_amdgcn_mfma_f32_16x16x32_f16(aq[mt][ss], kf[ct][ss], s[mt][ct], 0, 0, 0);

    if (it == NT - 1) {  // diagonal tile: causal mask
#pragma unroll
      for (int mt = 0; mt < 2; ++mt)
#pragma unroll
        for (int ct = 0; ct < 4; ++ct)
#pragma unroll
          for (int r = 0; r < 4; ++r)
            if (kv0 + ct * 16 + lrow > q0 + mt * 16 + g * 4 + r) s[mt][ct][r] = -1e30f;
    }

    // defer-max: in-lane partial maxima, full reduce only when THR exceeded
    float pm[2][4];
    bool need = false;
#pragma unroll
    for (int mt = 0; mt < 2; ++mt)
#pragma unroll
      for (int r = 0; r < 4; ++r) {
        pm[mt][r] = fmaxf(fmaxf(s[mt][0][r], s[mt][1][r]), fmaxf(s[mt][2][r], s[mt][3][r]));
        need = need || (pm[mt][r] > mrow[mt][r] + 8.f);
      }
    if (__any(need)) {  // slow path: full row max + rescale (first tile, rare after)
#pragma unroll
      for (int mt = 0; mt < 2; ++mt)
#pragma unroll
        for (int r = 0; r < 4; ++r) {
          float m = pm[mt][r];
          m = fmaxf(m, __shfl_xor(m, 1));
          m = fmaxf(m, __shfl_xor(m, 2));
          m = fmaxf(m, __shfl_xor(m, 4));
          m = fmaxf(m, __shfl_xor(m, 8));
          float mn = fmaxf(mrow[mt][r], m);
          float fr = __builtin_amdgcn_exp2f(mrow[mt][r] - mn);
          mrow[mt][r] = mn;
          lpart[mt][r] *= fr;
#pragma unroll
          for (int dt = 0; dt < 4; ++dt) o[mt][dt][r] *= fr;
        }
    }
    // exp + lane-partial sum + P (C/D layout) -> LDS in A-frag layout
#pragma unroll
    for (int mt = 0; mt < 2; ++mt)
#pragma unroll
      for (int r = 0; r < 4; ++r) {
        float ps = 0.f;
#pragma unroll
        for (int ct = 0; ct < 4; ++ct) {
          float p = __builtin_amdgcn_exp2f(s[mt][ct][r] - mrow[mt][r]);
          ps += p;
          pw[mt * 16 + g * 4 + r][ct * 16 + lrow] = (_Float16)p;
        }
        lpart[mt][r] += ps;
      }

    h8 ap[2][2];
#pragma unroll
    for (int mt = 0; mt < 2; ++mt)
#pragma unroll
      for (int ss = 0; ss < 2; ++ss)
        ap[mt][ss] = *(const h8*)&pw[mt * 16 + lrow][ss * 32 + g * 8];

#pragma unroll
    for (int ss = 0; ss < 2; ++ss)
#pragma unroll
      for (int mt = 0; mt < 2; ++mt)
#pragma unroll
        for (int dt = 0; dt < 4; ++dt)
          o[mt][dt] = __builtin_amdgcn_mfma_f32_16x16x32_f16(ap[mt][ss], vf[dt][ss], o[mt][dt], 0, 0, 0);
  }

  // ---- reduce l partials across the 16-lane row group (once) ----
#pragma unroll
  for (int mt = 0; mt < 2; ++mt)
#pragma unroll
    for (int r = 0; r < 4; ++r) {
      float l = lpart[mt][r];
      l += __shfl_xor(l, 1);
      l += __shfl_xor(l, 2);
      l += __shfl_xor(l, 4);
      l += __shfl_xor(l, 8);
      lpart[mt][r] = l;
    }

  // ---- write per-wave partials: m,l + NORMALIZED o (f16) into slab ----
  if (lrow == 0) {
#pragma unroll
    for (int mt = 0; mt < 2; ++mt)
#pragma unroll
      for (int r = 0; r < 4; ++r) {
        mlds[0][wave][mt * 16 + g * 4 + r] = mrow[mt][r];
        mlds[1][wave][mt * 16 + g * 4 + r] = lpart[mt][r];
      }
  }
#pragma unroll
  for (int mt = 0; mt < 2; ++mt)
#pragma unroll
    for (int r = 0; r < 4; ++r) {
      float inv = lpart[mt][r] > 0.f ? 1.f / lpart[mt][r] : 0.f;
#pragma unroll
      for (int dt = 0; dt < 4; ++dt)
        pw[mt * 16 + g * 4 + r][dt * 16 + lrow] = (_Float16)(o[mt][dt][r] * inv);
    }
  __syncthreads();

  // ---- merge 4 waves & write O (f16 [B,T,C]); weights f_w = exp2(m_w - M) * l_w ----
  {
    const int ql = threadIdx.x >> 3;        // 0..31
    const int d0 = (threadIdx.x & 7) * 8;   // 0..56
    float m0 = mlds[0][0][ql], m1 = mlds[0][1][ql], m2 = mlds[0][2][ql], m3 = mlds[0][3][ql];
    float M = fmaxf(fmaxf(m0, m1), fmaxf(m2, m3));
    float f0 = __builtin_amdgcn_exp2f(m0 - M) * mlds[1][0][ql];
    float f1 = __builtin_amdgcn_exp2f(m1 - M) * mlds[1][1][ql];
    float f2 = __builtin_amdgcn_exp2f(m2 - M) * mlds[1][2][ql];
    float f3 = __builtin_amdgcn_exp2f(m3 - M) * mlds[1][3][ql];
    float inv = 1.f / (f0 + f1 + f2 + f3);
    h8 o0 = *(const h8*)&slab[0][ql][d0];
    h8 o1 = *(const h8*)&slab[1][ql][d0];
    h8 o2 = *(const h8*)&slab[2][ql][d0];
    h8 o3 = *(const h8*)&slab[3][ql][d0];
    h8 outv;
#pragma unroll
    for (int j = 0; j < 8; ++j) {
      float v = f0 * (float)o0[j] + f1 * (float)o1[j] + f2 * (float)o2[j] + f3 * (float)o3[j];
      outv[j] = (_Float16)(v * inv);
    }
    *(h8*)&Og[((size_t)b * 2048 + q0 + ql) * 1024 + h * 64 + d0] = outv;
  }
}

// ---------------- launch ----------------
extern "C" void kernel_launch(void* const* d_in, const int* in_sizes, int n_in,
                              void* d_out, int out_size, void* d_ws, size_t ws_size,
                              hipStream_t stream) {
  const float* x = (const float*)d_in[0];       // [2,2048,1024]
  const float* Wqkv = (const float*)d_in[1];    // [1024,3072]
  const float* bqkv = (const float*)d_in[2];    // [3072]
  const float* Wproj = (const float*)d_in[3];   // [1024,1024]
  const float* bproj = (const float*)d_in[4];   // [1024]
  float* out = (float*)d_out;                   // [2,2048,1024] fp32

  char* ws = (char*)d_ws;
  const size_t MB = 1u << 20;
  _Float16* xh     = (_Float16*)(ws + 0 * MB);   // 4M f16 = 8MB
  _Float16* wqkvt  = (_Float16*)(ws + 8 * MB);   // [3072][1024] = 6MB
  _Float16* wprojt = (_Float16*)(ws + 14 * MB);  // [1024][1024] = 2MB
  _Float16* qh     = (_Float16*)(ws + 16 * MB);  // [B,H,T,D] = 8MB (pre-scaled)
  _Float16* kh     = (_Float16*)(ws + 24 * MB);  // [B,H,T,D] = 8MB
  _Float16* vth    = (_Float16*)(ws + 32 * MB);  // [B,H,D,T] = 8MB
  _Float16* oh     = (_Float16*)(ws + 40 * MB);  // [B,T,C]   = 8MB

  cast_f16_kernel<<<2048, 256, 0, stream>>>(x, xh, 4194304);
  transp_cast_kernel<<<dim3(48, 16), 256, 0, stream>>>(Wqkv, wqkvt, 1024, 3072);
  transp_cast_kernel<<<dim3(16, 16), 256, 0, stream>>>(Wproj, wprojt, 1024, 1024);

  gemm_f16<1><<<dim3(24, 32), 256, 0, stream>>>(xh, wqkvt, bqkv, nullptr, qh, kh, vth,
                                                4096, 3072, 1024);
  attn_kernel<<<dim3(2048), 256, 0, stream>>>(qh, kh, vth, oh);
  gemm_f16<0><<<dim3(8, 32), 256, 0, stream>>>(oh, wprojt, bproj, out, nullptr, nullptr, nullptr,
                                               4096, 1024, 1024);
}

// Round 4
// 161.132 us; speedup vs baseline: 1.3940x; 1.3940x over previous
//
#include <hip/hip_runtime.h>

typedef __attribute__((ext_vector_type(8))) _Float16 h8;
typedef __attribute__((ext_vector_type(4))) float f4;

#define QKSCALE 0.18033688011112042f  // 2^-3 * log2(e): fold softmax scale + exp2 conversion into Q

// ---------------- cast x (fp32 -> f16) ----------------
__global__ __launch_bounds__(256) void cast_f16_kernel(const float* __restrict__ in,
                                                       _Float16* __restrict__ out, int n) {
  int i = (blockIdx.x * 256 + threadIdx.x) * 8;
  if (i >= n) return;
  const float4* p = (const float4*)(in + i);
  float4 a = p[0], b = p[1];
  h8 v;
  v[0] = (_Float16)a.x; v[1] = (_Float16)a.y; v[2] = (_Float16)a.z; v[3] = (_Float16)a.w;
  v[4] = (_Float16)b.x; v[5] = (_Float16)b.y; v[6] = (_Float16)b.z; v[7] = (_Float16)b.w;
  *(h8*)(out + i) = v;
}

// ---------------- transpose-cast W [K][N] fp32 -> Wt [N][K] f16 ----------------
__global__ __launch_bounds__(256) void transp_cast_kernel(const float* __restrict__ W,
                                                          _Float16* __restrict__ Wt, int K, int N) {
  __shared__ _Float16 tile[64][72];
  int k0 = blockIdx.y * 64, n0 = blockIdx.x * 64;
  int t = threadIdx.x;
#pragma unroll
  for (int i = 0; i < 16; ++i) {
    int idx = i * 256 + t;
    int kr = idx >> 6, nc = idx & 63;
    tile[kr][nc] = (_Float16)W[(size_t)(k0 + kr) * N + n0 + nc];
  }
  __syncthreads();
#pragma unroll
  for (int i = 0; i < 2; ++i) {
    int idx = i * 256 + t;
    int nr = idx >> 3, kc = (idx & 7) * 8;
    h8 v;
#pragma unroll
    for (int j = 0; j < 8; ++j) v[j] = tile[kc + j][nr];
    *(h8*)&Wt[(size_t)(n0 + nr) * K + k0 + kc] = v;
  }
}

// ---------------- GEMM: C[M,N] = A[M,K] * Bt[N,K]^T (+bias), f16 MFMA ----------------
// MODE 0: outF fp32 row-major.  MODE 1: QKV scatter -> Q[B,H,T,D]*QKSCALE, K[B,H,T,D], V^T[B,H,D,T]
template <int MODE>
__global__ __launch_bounds__(256) void gemm_f16(const _Float16* __restrict__ A,
                                                const _Float16* __restrict__ Bt,
                                                const float* __restrict__ bias,
                                                float* __restrict__ outF,
                                                _Float16* __restrict__ oQ,
                                                _Float16* __restrict__ oK,
                                                _Float16* __restrict__ oV,
                                                int M, int N, int K) {
  __shared__ _Float16 As[128 * 64];
  __shared__ _Float16 Bs[128 * 64];
  const int m0 = blockIdx.y * 128, n0 = blockIdx.x * 128;
  const int tid = threadIdx.x;
  const int wave = tid >> 6, lane = tid & 63;
  const int wr = (wave >> 1) * 64, wc = (wave & 1) * 64;
  const int lrow = lane & 15, g = lane >> 4;
  f4 acc[4][4];
  const f4 z4 = {0.f, 0.f, 0.f, 0.f};
#pragma unroll
  for (int m = 0; m < 4; ++m)
#pragma unroll
    for (int n = 0; n < 4; ++n) acc[m][n] = z4;

  for (int k0 = 0; k0 < K; k0 += 64) {
    // stage A/B tiles [128 rows][64 k] with XOR chunk swizzle (chunk = 16B)
#pragma unroll
    for (int i = 0; i < 4; ++i) {
      int L = i * 256 + tid;
      int row = L >> 3, c = L & 7;
      int cs = (c ^ (row & 7)) * 8;
      *(h8*)&As[row * 64 + c * 8] = *(const h8*)&A[(size_t)(m0 + row) * K + k0 + cs];
      *(h8*)&Bs[row * 64 + c * 8] = *(const h8*)&Bt[(size_t)(n0 + row) * K + k0 + cs];
    }
    __syncthreads();
#pragma unroll
    for (int ss = 0; ss < 2; ++ss) {
      h8 af[4], bf[4];
#pragma unroll
      for (int m = 0; m < 4; ++m) {
        int row = wr + m * 16 + lrow;
        af[m] = *(const h8*)&As[row * 64 + (((ss * 4 + g) ^ (row & 7)) * 8)];
      }
#pragma unroll
      for (int n = 0; n < 4; ++n) {
        int row = wc + n * 16 + lrow;
        bf[n] = *(const h8*)&Bs[row * 64 + (((ss * 4 + g) ^ (row & 7)) * 8)];
      }
#pragma unroll
      for (int m = 0; m < 4; ++m)
#pragma unroll
        for (int n = 0; n < 4; ++n)
          acc[m][n] = __builtin_amdgcn_mfma_f32_16x16x32_f16(af[m], bf[n], acc[m][n], 0, 0, 0);
    }
    __syncthreads();
  }

  // epilogue; C/D layout: col = lane&15, row = (lane>>4)*4 + r  [m89]
#pragma unroll
  for (int n = 0; n < 4; ++n) {
    const int gcol = n0 + wc + n * 16 + lrow;
    const float bv = bias ? bias[gcol] : 0.f;
#pragma unroll
    for (int m = 0; m < 4; ++m) {
#pragma unroll
      for (int r = 0; r < 4; ++r) {
        const int grow = m0 + wr + m * 16 + g * 4 + r;
        float v = acc[m][n][r] + bv;
        if (MODE == 0) {
          outF[(size_t)grow * N + gcol] = v;
        } else {
          int part = gcol >> 10;
          int c1 = gcol & 1023;
          int hh = c1 >> 6, d = c1 & 63;
          int b = grow >> 11, t = grow & 2047;
          int bh = b * 16 + hh;
          if (part == 0)
            oQ[((size_t)bh * 2048 + t) * 64 + d] = (_Float16)(v * QKSCALE);
          else if (part == 1)
            oK[((size_t)bh * 2048 + t) * 64 + d] = (_Float16)v;
          else
            oV[((size_t)bh * 64 + d) * 2048 + t] = (_Float16)v;
        }
      }
    }
  }
}

// ---------------- flash attention v4: split-KV, low-LDS, defer-max, natural regalloc ----
// Block = 32 q-rows. 4 waves split KV tiles (it = wave, wave+4, ...), merge at end.
// slab[wave] is P staging during the loop, then reused for NORMALIZED (o/l) f16
// O partials. l kept as per-lane partials, reduced once after the loop.
// Defer-max (THR=8): fast-path iterations have zero cross-lane ops.
// NO launch-bounds occupancy hint: r3 showed forcing the VGPR cap (->64) turns
// this into a scratch-spill kernel (WRITE_SIZE 8MB -> 310MB). Natural alloc ~124.
__global__ __launch_bounds__(256) void attn_kernel(const _Float16* __restrict__ Qg,
                                                   const _Float16* __restrict__ Kg,
                                                   const _Float16* __restrict__ Vtg,
                                                   _Float16* __restrict__ Og) {
  __shared__ _Float16 slab[4][32][72];  // P staging -> normalized O partials (f16)
  __shared__ float mlds[2][4][32];      // [0]=m, [1]=l per wave per q-row

  const int idx = blockIdx.x;
  // XCD-affinity (%8 round-robin) + longest-first (high qt2 dispatched first)
  const int bh = (idx & 7) | (((idx >> 3) & 3) << 3);
  const int qt2 = 63 - (idx >> 5);
  const int q0 = qt2 * 32;

  const int wave = threadIdx.x >> 6, lane = threadIdx.x & 63;
  const int lrow = lane & 15, g = lane >> 4;
  const int b = bh >> 4, h = bh & 15;
  const _Float16* Q = Qg + (size_t)bh * 2048 * 64;
  const _Float16* K = Kg + (size_t)bh * 2048 * 64;
  const _Float16* Vt = Vtg + (size_t)bh * 64 * 2048;

  h8 aq[2][2];
#pragma unroll
  for (int mt = 0; mt < 2; ++mt)
#pragma unroll
    for (int ss = 0; ss < 2; ++ss)
      aq[mt][ss] = *(const h8*)&Q[(q0 + mt * 16 + lrow) * 64 + ss * 32 + g * 8];

  const f4 z4 = {0.f, 0.f, 0.f, 0.f};
  f4 o[2][4];
#pragma unroll
  for (int mt = 0; mt < 2; ++mt)
#pragma unroll
    for (int dt = 0; dt < 4; ++dt) o[mt][dt] = z4;
  float mrow[2][4], lpart[2][4];
#pragma unroll
  for (int mt = 0; mt < 2; ++mt)
#pragma unroll
    for (int r = 0; r < 4; ++r) { mrow[mt][r] = -1e30f; lpart[mt][r] = 0.f; }

  _Float16(*pw)[72] = slab[wave];
  const int NT = (qt2 >> 1) + 1;  // KV tiles of 64 covering rows [q0, q0+32)

  for (int it = wave; it < NT; it += 4) {
    const int kv0 = it * 64;
    // K fragment loads
    h8 kf[4][2];
#pragma unroll
    for (int ct = 0; ct < 4; ++ct)
#pragma unroll
      for (int ss = 0; ss < 2; ++ss)
        kf[ct][ss] = *(const h8*)&K[(kv0 + ct * 16 + lrow) * 64 + ss * 32 + g * 8];

    f4 s[2][4];
#pragma unroll
    for (int mt = 0; mt < 2; ++mt)
#pragma unroll
      for (int ct = 0; ct < 4; ++ct) s[mt][ct] = z4;
#pragma unroll
    for (int ss = 0; ss < 2; ++ss)
#pragma unroll
      for (int mt = 0; mt < 2; ++mt)
#pragma unroll
        for (int ct = 0; ct < 4; ++ct)
          s[mt][ct] = __builtin_amdgcn_mfma_f32_16x16x32_f16(aq[mt][ss], kf[ct][ss], s[mt][ct], 0, 0, 0);

    // V fragment loads issued here: after QK (kf dead -> lower peak pressure),
    // before softmax (latency hides under the VALU chain)
    h8 vf[4][2];
#pragma unroll
    for (int dt = 0; dt < 4; ++dt)
#pragma unroll
      for (int ss = 0; ss < 2; ++ss)
        vf[dt][ss] = *(const h8*)&Vt[(size_t)(dt * 16 + lrow) * 2048 + kv0 + ss * 32 + g * 8];

    if (it == NT - 1) {  // diagonal tile: causal mask
#pragma unroll
      for (int mt = 0; mt < 2; ++mt)
#pragma unroll
        for (int ct = 0; ct < 4; ++ct)
#pragma unroll
          for (int r = 0; r < 4; ++r)
            if (kv0 + ct * 16 + lrow > q0 + mt * 16 + g * 4 + r) s[mt][ct][r] = -1e30f;
    }

    // defer-max: in-lane partial maxima, full reduce only when THR exceeded
    float pm[2][4];
    bool need = false;
#pragma unroll
    for (int mt = 0; mt < 2; ++mt)
#pragma unroll
      for (int r = 0; r < 4; ++r) {
        pm[mt][r] = fmaxf(fmaxf(s[mt][0][r], s[mt][1][r]), fmaxf(s[mt][2][r], s[mt][3][r]));
        need = need || (pm[mt][r] > mrow[mt][r] + 8.f);
      }
    if (__any(need)) {  // slow path: full row max + rescale (first tile, rare after)
#pragma unroll
      for (int mt = 0; mt < 2; ++mt)
#pragma unroll
        for (int r = 0; r < 4; ++r) {
          float m = pm[mt][r];
          m = fmaxf(m, __shfl_xor(m, 1));
          m = fmaxf(m, __shfl_xor(m, 2));
          m = fmaxf(m, __shfl_xor(m, 4));
          m = fmaxf(m, __shfl_xor(m, 8));
          float mn = fmaxf(mrow[mt][r], m);
          float fr = __builtin_amdgcn_exp2f(mrow[mt][r] - mn);
          mrow[mt][r] = mn;
          lpart[mt][r] *= fr;
#pragma unroll
          for (int dt = 0; dt < 4; ++dt) o[mt][dt][r] *= fr;
        }
    }
    // exp + lane-partial sum + P (C/D layout) -> LDS in A-frag layout
#pragma unroll
    for (int mt = 0; mt < 2; ++mt)
#pragma unroll
      for (int r = 0; r < 4; ++r) {
        float ps = 0.f;
#pragma unroll
        for (int ct = 0; ct < 4; ++ct) {
          float p = __builtin_amdgcn_exp2f(s[mt][ct][r] - mrow[mt][r]);
          ps += p;
          pw[mt * 16 + g * 4 + r][ct * 16 + lrow] = (_Float16)p;
        }
        lpart[mt][r] += ps;
      }

    h8 ap[2][2];
#pragma unroll
    for (int mt = 0; mt < 2; ++mt)
#pragma unroll
      for (int ss = 0; ss < 2; ++ss)
        ap[mt][ss] = *(const h8*)&pw[mt * 16 + lrow][ss * 32 + g * 8];

#pragma unroll
    for (int ss = 0; ss < 2; ++ss)
#pragma unroll
      for (int mt = 0; mt < 2; ++mt)
#pragma unroll
        for (int dt = 0; dt < 4; ++dt)
          o[mt][dt] = __builtin_amdgcn_mfma_f32_16x16x32_f16(ap[mt][ss], vf[dt][ss], o[mt][dt], 0, 0, 0);
  }

  // ---- reduce l partials across the 16-lane row group (once) ----
#pragma unroll
  for (int mt = 0; mt < 2; ++mt)
#pragma unroll
    for (int r = 0; r < 4; ++r) {
      float l = lpart[mt][r];
      l += __shfl_xor(l, 1);
      l += __shfl_xor(l, 2);
      l += __shfl_xor(l, 4);
      l += __shfl_xor(l, 8);
      lpart[mt][r] = l;
    }

  // ---- write per-wave partials: m,l + NORMALIZED o (f16) into slab ----
  if (lrow == 0) {
#pragma unroll
    for (int mt = 0; mt < 2; ++mt)
#pragma unroll
      for (int r = 0; r < 4; ++r) {
        mlds[0][wave][mt * 16 + g * 4 + r] = mrow[mt][r];
        mlds[1][wave][mt * 16 + g * 4 + r] = lpart[mt][r];
      }
  }
#pragma unroll
  for (int mt = 0; mt < 2; ++mt)
#pragma unroll
    for (int r = 0; r < 4; ++r) {
      float inv = lpart[mt][r] > 0.f ? 1.f / lpart[mt][r] : 0.f;
#pragma unroll
      for (int dt = 0; dt < 4; ++dt)
        pw[mt * 16 + g * 4 + r][dt * 16 + lrow] = (_Float16)(o[mt][dt][r] * inv);
    }
  __syncthreads();

  // ---- merge 4 waves & write O (f16 [B,T,C]); weights f_w = exp2(m_w - M) * l_w ----
  {
    const int ql = threadIdx.x >> 3;        // 0..31
    const int d0 = (threadIdx.x & 7) * 8;   // 0..56
    float m0 = mlds[0][0][ql], m1 = mlds[0][1][ql], m2 = mlds[0][2][ql], m3 = mlds[0][3][ql];
    float M = fmaxf(fmaxf(m0, m1), fmaxf(m2, m3));
    float f0 = __builtin_amdgcn_exp2f(m0 - M) * mlds[1][0][ql];
    float f1 = __builtin_amdgcn_exp2f(m1 - M) * mlds[1][1][ql];
    float f2 = __builtin_amdgcn_exp2f(m2 - M) * mlds[1][2][ql];
    float f3 = __builtin_amdgcn_exp2f(m3 - M) * mlds[1][3][ql];
    float inv = 1.f / (f0 + f1 + f2 + f3);
    h8 o0 = *(const h8*)&slab[0][ql][d0];
    h8 o1 = *(const h8*)&slab[1][ql][d0];
    h8 o2 = *(const h8*)&slab[2][ql][d0];
    h8 o3 = *(const h8*)&slab[3][ql][d0];
    h8 outv;
#pragma unroll
    for (int j = 0; j < 8; ++j) {
      float v = f0 * (float)o0[j] + f1 * (float)o1[j] + f2 * (float)o2[j] + f3 * (float)o3[j];
      outv[j] = (_Float16)(v * inv);
    }
    *(h8*)&Og[((size_t)b * 2048 + q0 + ql) * 1024 + h * 64 + d0] = outv;
  }
}

// ---------------- launch ----------------
extern "C" void kernel_launch(void* const* d_in, const int* in_sizes, int n_in,
                              void* d_out, int out_size, void* d_ws, size_t ws_size,
                              hipStream_t stream) {
  const float* x = (const float*)d_in[0];       // [2,2048,1024]
  const float* Wqkv = (const float*)d_in[1];    // [1024,3072]
  const float* bqkv = (const float*)d_in[2];    // [3072]
  const float* Wproj = (const float*)d_in[3];   // [1024,1024]
  const float* bproj = (const float*)d_in[4];   // [1024]
  float* out = (float*)d_out;                   // [2,2048,1024] fp32

  char* ws = (char*)d_ws;
  const size_t MB = 1u << 20;
  _Float16* xh     = (_Float16*)(ws + 0 * MB);   // 4M f16 = 8MB
  _Float16* wqkvt  = (_Float16*)(ws + 8 * MB);   // [3072][1024] = 6MB
  _Float16* wprojt = (_Float16*)(ws + 14 * MB);  // [1024][1024] = 2MB
  _Float16* qh     = (_Float16*)(ws + 16 * MB);  // [B,H,T,D] = 8MB (pre-scaled)
  _Float16* kh     = (_Float16*)(ws + 24 * MB);  // [B,H,T,D] = 8MB
  _Float16* vth    = (_Float16*)(ws + 32 * MB);  // [B,H,D,T] = 8MB
  _Float16* oh     = (_Float16*)(ws + 40 * MB);  // [B,T,C]   = 8MB

  cast_f16_kernel<<<2048, 256, 0, stream>>>(x, xh, 4194304);
  transp_cast_kernel<<<dim3(48, 16), 256, 0, stream>>>(Wqkv, wqkvt, 1024, 3072);
  transp_cast_kernel<<<dim3(16, 16), 256, 0, stream>>>(Wproj, wprojt, 1024, 1024);

  gemm_f16<1><<<dim3(24, 32), 256, 0, stream>>>(xh, wqkvt, bqkv, nullptr, qh, kh, vth,
                                                4096, 3072, 1024);
  attn_kernel<<<dim3(2048), 256, 0, stream>>>(qh, kh, vth, oh);
  gemm_f16<0><<<dim3(8, 32), 256, 0, stream>>>(oh, wprojt, bproj, out, nullptr, nullptr, nullptr,
                                               4096, 1024, 1024);
}

// Round 5
// 152.829 us; speedup vs baseline: 1.4697x; 1.0543x over previous
//
#include <hip/hip_runtime.h>

typedef __attribute__((ext_vector_type(8))) _Float16 h8;
typedef __attribute__((ext_vector_type(4))) _Float16 h4;
typedef __attribute__((ext_vector_type(4))) float f4;

#define QKSCALE 0.18033688011112042f  // 2^-3 * log2(e): fold softmax scale + exp2 conversion into Q

// async global->LDS, 16B per lane (dest must be lane-linear; source may be per-lane swizzled)
__device__ __forceinline__ void gload16(const void* g, void* l) {
  __builtin_amdgcn_global_load_lds((const __attribute__((address_space(1))) void*)g,
                                   (__attribute__((address_space(3))) void*)l, 16, 0, 0);
}

// ---------------- cast x (fp32 -> f16) ----------------
__global__ __launch_bounds__(256) void cast_f16_kernel(const float* __restrict__ in,
                                                       _Float16* __restrict__ out, int n) {
  int i = (blockIdx.x * 256 + threadIdx.x) * 8;
  if (i >= n) return;
  const float4* p = (const float4*)(in + i);
  float4 a = p[0], b = p[1];
  h8 v;
  v[0] = (_Float16)a.x; v[1] = (_Float16)a.y; v[2] = (_Float16)a.z; v[3] = (_Float16)a.w;
  v[4] = (_Float16)b.x; v[5] = (_Float16)b.y; v[6] = (_Float16)b.z; v[7] = (_Float16)b.w;
  *(h8*)(out + i) = v;
}

// ---------------- transpose-cast W [K][N] fp32 -> Wt [N][K] f16 ----------------
__global__ __launch_bounds__(256) void transp_cast_kernel(const float* __restrict__ W,
                                                          _Float16* __restrict__ Wt, int K, int N) {
  __shared__ _Float16 tile[64][72];
  int k0 = blockIdx.y * 64, n0 = blockIdx.x * 64;
  int t = threadIdx.x;
#pragma unroll
  for (int i = 0; i < 16; ++i) {
    int idx = i * 256 + t;
    int kr = idx >> 6, nc = idx & 63;
    tile[kr][nc] = (_Float16)W[(size_t)(k0 + kr) * N + n0 + nc];
  }
  __syncthreads();
#pragma unroll
  for (int i = 0; i < 2; ++i) {
    int idx = i * 256 + t;
    int nr = idx >> 3, kc = (idx & 7) * 8;
    h8 v;
#pragma unroll
    for (int j = 0; j < 8; ++j) v[j] = tile[kc + j][nr];
    *(h8*)&Wt[(size_t)(n0 + nr) * K + k0 + kc] = v;
  }
}

// ---------------- GEMM: C[M,N] = A[M,K] * Bt[N,K]^T (+bias), f16 MFMA ----------------
// Staging via global_load_lds width=16 (m97 pattern): LDS dest lane-linear,
// XOR chunk swizzle applied to the SOURCE address; reads XOR the chunk index.
// MODE 0: outF fp32 row-major.  MODE 1: QKV scatter -> Q[B,H,T,D]*QKSCALE, K[B,H,T,D], V^T[B,H,D,T]
template <int MODE>
__global__ __launch_bounds__(256) void gemm_f16(const _Float16* __restrict__ A,
                                                const _Float16* __restrict__ Bt,
                                                const float* __restrict__ bias,
                                                float* __restrict__ outF,
                                                _Float16* __restrict__ oQ,
                                                _Float16* __restrict__ oK,
                                                _Float16* __restrict__ oV,
                                                int M, int N, int K) {
  __shared__ _Float16 As[128 * 64];
  __shared__ _Float16 Bs[128 * 64];
  const int m0 = blockIdx.y * 128, n0 = blockIdx.x * 128;
  const int tid = threadIdx.x;
  const int wave = tid >> 6, lane = tid & 63;
  const int wr = (wave >> 1) * 64, wc = (wave & 1) * 64;
  const int lrow = lane & 15, g = lane >> 4;

  // per-thread staging slot: L = i*256 + tid -> row = L>>3, chunk slot c = L&7
  // source chunk = c ^ (row&7); LDS dest = L*16 bytes (lane-linear within wave)
  const int row_ = tid >> 3, c_ = tid & 7;

  f4 acc[4][4];
  const f4 z4 = {0.f, 0.f, 0.f, 0.f};
#pragma unroll
  for (int m = 0; m < 4; ++m)
#pragma unroll
    for (int n = 0; n < 4; ++n) acc[m][n] = z4;

  for (int k0 = 0; k0 < K; k0 += 64) {
#pragma unroll
    for (int i = 0; i < 4; ++i) {
      int row = i * 32 + row_;                 // L = i*256 + tid, row = L>>3
      int cs = (c_ ^ (row & 7)) * 8;           // swizzled source chunk
      int ldst = (i * 256 + tid) * 8;          // LDS element offset (16B per thread)
      gload16(&A[(size_t)(m0 + row) * K + k0 + cs], &As[ldst]);
      gload16(&Bt[(size_t)(n0 + row) * K + k0 + cs], &Bs[ldst]);
    }
    __syncthreads();  // drains vmcnt -> tiles ready
#pragma unroll
    for (int ss = 0; ss < 2; ++ss) {
      h8 af[4], bf[4];
#pragma unroll
      for (int m = 0; m < 4; ++m) {
        int row = wr + m * 16 + lrow;
        af[m] = *(const h8*)&As[row * 64 + (((ss * 4 + g) ^ (row & 7)) * 8)];
      }
#pragma unroll
      for (int n = 0; n < 4; ++n) {
        int row = wc + n * 16 + lrow;
        bf[n] = *(const h8*)&Bs[row * 64 + (((ss * 4 + g) ^ (row & 7)) * 8)];
      }
      __builtin_amdgcn_s_setprio(1);
#pragma unroll
      for (int m = 0; m < 4; ++m)
#pragma unroll
        for (int n = 0; n < 4; ++n)
          acc[m][n] = __builtin_amdgcn_mfma_f32_16x16x32_f16(af[m], bf[n], acc[m][n], 0, 0, 0);
      __builtin_amdgcn_s_setprio(0);
    }
    __syncthreads();
  }

  // epilogue; C/D layout: col = lane&15, row = (lane>>4)*4 + r  [m89]
#pragma unroll
  for (int n = 0; n < 4; ++n) {
    const int gcol = n0 + wc + n * 16 + lrow;
    const float bv = bias ? bias[gcol] : 0.f;
    if (MODE == 1 && (gcol >> 10) == 2) {
      // V part: pack 4 r-consecutive t values into one 8B store (V^T is [B,H,D,T])
      const int c1 = gcol & 1023;
      const int hh = c1 >> 6, d = c1 & 63;
#pragma unroll
      for (int m = 0; m < 4; ++m) {
        const int grow = m0 + wr + m * 16 + g * 4;  // r=0 row; 4 consecutive t
        const int b = grow >> 11, t = grow & 2047;
        h4 pv;
#pragma unroll
        for (int r = 0; r < 4; ++r) pv[r] = (_Float16)(acc[m][n][r] + bv);
        *(h4*)&oV[(((size_t)(b * 16 + hh)) * 64 + d) * 2048 + t] = pv;
      }
    } else {
#pragma unroll
      for (int m = 0; m < 4; ++m) {
#pragma unroll
        for (int r = 0; r < 4; ++r) {
          const int grow = m0 + wr + m * 16 + g * 4 + r;
          float v = acc[m][n][r] + bv;
          if (MODE == 0) {
            outF[(size_t)grow * N + gcol] = v;
          } else {
            int part = gcol >> 10;
            int c1 = gcol & 1023;
            int hh = c1 >> 6, d = c1 & 63;
            int b = grow >> 11, t = grow & 2047;
            int bh = b * 16 + hh;
            if (part == 0)
              oQ[((size_t)bh * 2048 + t) * 64 + d] = (_Float16)(v * QKSCALE);
            else
              oK[((size_t)bh * 2048 + t) * 64 + d] = (_Float16)v;
          }
        }
      }
    }
  }
}

// ---------------- flash attention v5: split-KV, low-LDS, defer-max, setprio ----
// Block = 32 q-rows. 4 waves split KV tiles (it = wave, wave+4, ...), merge at end.
// slab[wave] is P staging during the loop, then reused for NORMALIZED (o/l) f16
// O partials. l kept as per-lane partials, reduced once after the loop.
// Defer-max (THR=8): fast-path iterations have zero cross-lane ops.
// NO launch-bounds occupancy hint (r3: forced cap -> 310MB scratch spill).
__global__ __launch_bounds__(256) void attn_kernel(const _Float16* __restrict__ Qg,
                                                   const _Float16* __restrict__ Kg,
                                                   const _Float16* __restrict__ Vtg,
                                                   _Float16* __restrict__ Og) {
  __shared__ _Float16 slab[4][32][72];  // P staging -> normalized O partials (f16)
  __shared__ float mlds[2][4][32];      // [0]=m, [1]=l per wave per q-row

  const int idx = blockIdx.x;
  // XCD-affinity (%8 round-robin) + longest-first (high qt2 dispatched first)
  const int bh = (idx & 7) | (((idx >> 3) & 3) << 3);
  const int qt2 = 63 - (idx >> 5);
  const int q0 = qt2 * 32;

  const int wave = threadIdx.x >> 6, lane = threadIdx.x & 63;
  const int lrow = lane & 15, g = lane >> 4;
  const int b = bh >> 4, h = bh & 15;
  const _Float16* Q = Qg + (size_t)bh * 2048 * 64;
  const _Float16* K = Kg + (size_t)bh * 2048 * 64;
  const _Float16* Vt = Vtg + (size_t)bh * 64 * 2048;

  h8 aq[2][2];
#pragma unroll
  for (int mt = 0; mt < 2; ++mt)
#pragma unroll
    for (int ss = 0; ss < 2; ++ss)
      aq[mt][ss] = *(const h8*)&Q[(q0 + mt * 16 + lrow) * 64 + ss * 32 + g * 8];

  const f4 z4 = {0.f, 0.f, 0.f, 0.f};
  f4 o[2][4];
#pragma unroll
  for (int mt = 0; mt < 2; ++mt)
#pragma unroll
    for (int dt = 0; dt < 4; ++dt) o[mt][dt] = z4;
  float mrow[2][4], lpart[2][4];
#pragma unroll
  for (int mt = 0; mt < 2; ++mt)
#pragma unroll
    for (int r = 0; r < 4; ++r) { mrow[mt][r] = -1e30f; lpart[mt][r] = 0.f; }

  _Float16(*pw)[72] = slab[wave];
  const int NT = (qt2 >> 1) + 1;  // KV tiles of 64 covering rows [q0, q0+32)

  for (int it = wave; it < NT; it += 4) {
    const int kv0 = it * 64;
    // K fragment loads
    h8 kf[4][2];
#pragma unroll
    for (int ct = 0; ct < 4; ++ct)
#pragma unroll
      for (int ss = 0; ss < 2; ++ss)
        kf[ct][ss] = *(const h8*)&K[(kv0 + ct * 16 + lrow) * 64 + ss * 32 + g * 8];

    f4 s[2][4];
#pragma unroll
    for (int mt = 0; mt < 2; ++mt)
#pragma unroll
      for (int ct = 0; ct < 4; ++ct) s[mt][ct] = z4;
    __builtin_amdgcn_s_setprio(1);
#pragma unroll
    for (int ss = 0; ss < 2; ++ss)
#pragma unroll
      for (int mt = 0; mt < 2; ++mt)
#pragma unroll
        for (int ct = 0; ct < 4; ++ct)
          s[mt][ct] = __builtin_amdgcn_mfma_f32_16x16x32_f16(aq[mt][ss], kf[ct][ss], s[mt][ct], 0, 0, 0);
    __builtin_amdgcn_s_setprio(0);

    // V fragment loads issued here: after QK (kf dead -> lower peak pressure),
    // before softmax (latency hides under the VALU chain)
    h8 vf[4][2];
#pragma unroll
    for (int dt = 0; dt < 4; ++dt)
#pragma unroll
      for (int ss = 0; ss < 2; ++ss)
        vf[dt][ss] = *(const h8*)&Vt[(size_t)(dt * 16 + lrow) * 2048 + kv0 + ss * 32 + g * 8];

    if (it == NT - 1) {  // diagonal tile: causal mask
#pragma unroll
      for (int mt = 0; mt < 2; ++mt)
#pragma unroll
        for (int ct = 0; ct < 4; ++ct)
#pragma unroll
          for (int r = 0; r < 4; ++r)
            if (kv0 + ct * 16 + lrow > q0 + mt * 16 + g * 4 + r) s[mt][ct][r] = -1e30f;
    }

    // defer-max: in-lane partial maxima, full reduce only when THR exceeded
    float pm[2][4];
    bool need = false;
#pragma unroll
    for (int mt = 0; mt < 2; ++mt)
#pragma unroll
      for (int r = 0; r < 4; ++r) {
        pm[mt][r] = fmaxf(fmaxf(s[mt][0][r], s[mt][1][r]), fmaxf(s[mt][2][r], s[mt][3][r]));
        need = need || (pm[mt][r] > mrow[mt][r] + 8.f);
      }
    if (__any(need)) {  // slow path: full row max + rescale (first tile, rare after)
#pragma unroll
      for (int mt = 0; mt < 2; ++mt)
#pragma unroll
        for (int r = 0; r < 4; ++r) {
          float m = pm[mt][r];
          m = fmaxf(m, __shfl_xor(m, 1));
          m = fmaxf(m, __shfl_xor(m, 2));
          m = fmaxf(m, __shfl_xor(m, 4));
          m = fmaxf(m, __shfl_xor(m, 8));
          float mn = fmaxf(mrow[mt][r], m);
          float fr = __builtin_amdgcn_exp2f(mrow[mt][r] - mn);
          mrow[mt][r] = mn;
          lpart[mt][r] *= fr;
#pragma unroll
          for (int dt = 0; dt < 4; ++dt) o[mt][dt][r] *= fr;
        }
    }
    // exp + lane-partial sum + P (C/D layout) -> LDS in A-frag layout
#pragma unroll
    for (int mt = 0; mt < 2; ++mt)
#pragma unroll
      for (int r = 0; r < 4; ++r) {
        float ps = 0.f;
#pragma unroll
        for (int ct = 0; ct < 4; ++ct) {
          float p = __builtin_amdgcn_exp2f(s[mt][ct][r] - mrow[mt][r]);
          ps += p;
          pw[mt * 16 + g * 4 + r][ct * 16 + lrow] = (_Float16)p;
        }
        lpart[mt][r] += ps;
      }

    h8 ap[2][2];
#pragma unroll
    for (int mt = 0; mt < 2; ++mt)
#pragma unroll
      for (int ss = 0; ss < 2; ++ss)
        ap[mt][ss] = *(const h8*)&pw[mt * 16 + lrow][ss * 32 + g * 8];

    __builtin_amdgcn_s_setprio(1);
#pragma unroll
    for (int ss = 0; ss < 2; ++ss)
#pragma unroll
      for (int mt = 0; mt < 2; ++mt)
#pragma unroll
        for (int dt = 0; dt < 4; ++dt)
          o[mt][dt] = __builtin_amdgcn_mfma_f32_16x16x32_f16(ap[mt][ss], vf[dt][ss], o[mt][dt], 0, 0, 0);
    __builtin_amdgcn_s_setprio(0);
  }

  // ---- reduce l partials across the 16-lane row group (once) ----
#pragma unroll
  for (int mt = 0; mt < 2; ++mt)
#pragma unroll
    for (int r = 0; r < 4; ++r) {
      float l = lpart[mt][r];
      l += __shfl_xor(l, 1);
      l += __shfl_xor(l, 2);
      l += __shfl_xor(l, 4);
      l += __shfl_xor(l, 8);
      lpart[mt][r] = l;
    }

  // ---- write per-wave partials: m,l + NORMALIZED o (f16) into slab ----
  if (lrow == 0) {
#pragma unroll
    for (int mt = 0; mt < 2; ++mt)
#pragma unroll
      for (int r = 0; r < 4; ++r) {
        mlds[0][wave][mt * 16 + g * 4 + r] = mrow[mt][r];
        mlds[1][wave][mt * 16 + g * 4 + r] = lpart[mt][r];
      }
  }
#pragma unroll
  for (int mt = 0; mt < 2; ++mt)
#pragma unroll
    for (int r = 0; r < 4; ++r) {
      float inv = lpart[mt][r] > 0.f ? 1.f / lpart[mt][r] : 0.f;
#pragma unroll
      for (int dt = 0; dt < 4; ++dt)
        pw[mt * 16 + g * 4 + r][dt * 16 + lrow] = (_Float16)(o[mt][dt][r] * inv);
    }
  __syncthreads();

  // ---- merge 4 waves & write O (f16 [B,T,C]); weights f_w = exp2(m_w - M) * l_w ----
  {
    const int ql = threadIdx.x >> 3;        // 0..31
    const int d0 = (threadIdx.x & 7) * 8;   // 0..56
    float m0 = mlds[0][0][ql], m1 = mlds[0][1][ql], m2 = mlds[0][2][ql], m3 = mlds[0][3][ql];
    float M = fmaxf(fmaxf(m0, m1), fmaxf(m2, m3));
    float f0 = __builtin_amdgcn_exp2f(m0 - M) * mlds[1][0][ql];
    float f1 = __builtin_amdgcn_exp2f(m1 - M) * mlds[1][1][ql];
    float f2 = __builtin_amdgcn_exp2f(m2 - M) * mlds[1][2][ql];
    float f3 = __builtin_amdgcn_exp2f(m3 - M) * mlds[1][3][ql];
    float inv = 1.f / (f0 + f1 + f2 + f3);
    h8 o0 = *(const h8*)&slab[0][ql][d0];
    h8 o1 = *(const h8*)&slab[1][ql][d0];
    h8 o2 = *(const h8*)&slab[2][ql][d0];
    h8 o3 = *(const h8*)&slab[3][ql][d0];
    h8 outv;
#pragma unroll
    for (int j = 0; j < 8; ++j) {
      float v = f0 * (float)o0[j] + f1 * (float)o1[j] + f2 * (float)o2[j] + f3 * (float)o3[j];
      outv[j] = (_Float16)(v * inv);
    }
    *(h8*)&Og[((size_t)b * 2048 + q0 + ql) * 1024 + h * 64 + d0] = outv;
  }
}

// ---------------- launch ----------------
extern "C" void kernel_launch(void* const* d_in, const int* in_sizes, int n_in,
                              void* d_out, int out_size, void* d_ws, size_t ws_size,
                              hipStream_t stream) {
  const float* x = (const float*)d_in[0];       // [2,2048,1024]
  const float* Wqkv = (const float*)d_in[1];    // [1024,3072]
  const float* bqkv = (const float*)d_in[2];    // [3072]
  const float* Wproj = (const float*)d_in[3];   // [1024,1024]
  const float* bproj = (const float*)d_in[4];   // [1024]
  float* out = (float*)d_out;                   // [2,2048,1024] fp32

  char* ws = (char*)d_ws;
  const size_t MB = 1u << 20;
  _Float16* xh     = (_Float16*)(ws + 0 * MB);   // 4M f16 = 8MB
  _Float16* wqkvt  = (_Float16*)(ws + 8 * MB);   // [3072][1024] = 6MB
  _Float16* wprojt = (_Float16*)(ws + 14 * MB);  // [1024][1024] = 2MB
  _Float16* qh     = (_Float16*)(ws + 16 * MB);  // [B,H,T,D] = 8MB (pre-scaled)
  _Float16* kh     = (_Float16*)(ws + 24 * MB);  // [B,H,T,D] = 8MB
  _Float16* vth    = (_Float16*)(ws + 32 * MB);  // [B,H,D,T] = 8MB
  _Float16* oh     = (_Float16*)(ws + 40 * MB);  // [B,T,C]   = 8MB

  cast_f16_kernel<<<2048, 256, 0, stream>>>(x, xh, 4194304);
  transp_cast_kernel<<<dim3(48, 16), 256, 0, stream>>>(Wqkv, wqkvt, 1024, 3072);
  transp_cast_kernel<<<dim3(16, 16), 256, 0, stream>>>(Wproj, wprojt, 1024, 1024);

  gemm_f16<1><<<dim3(24, 32), 256, 0, stream>>>(xh, wqkvt, bqkv, nullptr, qh, kh, vth,
                                                4096, 3072, 1024);
  attn_kernel<<<dim3(2048), 256, 0, stream>>>(qh, kh, vth, oh);
  gemm_f16<0><<<dim3(8, 32), 256, 0, stream>>>(oh, wprojt, bproj, out, nullptr, nullptr, nullptr,
                                               4096, 1024, 1024);
}

// Round 6
// 151.768 us; speedup vs baseline: 1.4800x; 1.0070x over previous
//
#include <hip/hip_runtime.h>

typedef __attribute__((ext_vector_type(8))) _Float16 h8;
typedef __attribute__((ext_vector_type(4))) _Float16 h4;
typedef __attribute__((ext_vector_type(4))) float f4;

#define QKSCALE 0.18033688011112042f  // 2^-3 * log2(e): fold softmax scale + exp2 conversion into Q

// async global->LDS, 16B per lane (dest must be lane-linear; source may be per-lane swizzled)
__device__ __forceinline__ void gload16(const void* g, void* l) {
  __builtin_amdgcn_global_load_lds((const __attribute__((address_space(1))) void*)g,
                                   (__attribute__((address_space(3))) void*)l, 16, 0, 0);
}

// ---------------- cast x (fp32 -> f16) ----------------
__global__ __launch_bounds__(256) void cast_f16_kernel(const float* __restrict__ in,
                                                       _Float16* __restrict__ out, int n) {
  int i = (blockIdx.x * 256 + threadIdx.x) * 8;
  if (i >= n) return;
  const float4* p = (const float4*)(in + i);
  float4 a = p[0], b = p[1];
  h8 v;
  v[0] = (_Float16)a.x; v[1] = (_Float16)a.y; v[2] = (_Float16)a.z; v[3] = (_Float16)a.w;
  v[4] = (_Float16)b.x; v[5] = (_Float16)b.y; v[6] = (_Float16)b.z; v[7] = (_Float16)b.w;
  *(h8*)(out + i) = v;
}

// ---------------- transpose-cast W [K][N] fp32 -> Wt [N][K] f16 ----------------
__global__ __launch_bounds__(256) void transp_cast_kernel(const float* __restrict__ W,
                                                          _Float16* __restrict__ Wt, int K, int N) {
  __shared__ _Float16 tile[64][72];
  int k0 = blockIdx.y * 64, n0 = blockIdx.x * 64;
  int t = threadIdx.x;
#pragma unroll
  for (int i = 0; i < 16; ++i) {
    int idx = i * 256 + t;
    int kr = idx >> 6, nc = idx & 63;
    tile[kr][nc] = (_Float16)W[(size_t)(k0 + kr) * N + n0 + nc];
  }
  __syncthreads();
#pragma unroll
  for (int i = 0; i < 2; ++i) {
    int idx = i * 256 + t;
    int nr = idx >> 3, kc = (idx & 7) * 8;
    h8 v;
#pragma unroll
    for (int j = 0; j < 8; ++j) v[j] = tile[kc + j][nr];
    *(h8*)&Wt[(size_t)(n0 + nr) * K + k0 + kc] = v;
  }
}

// ---------------- GEMM: C[M,N] = A[M,K] * Bt[N,K]^T (+bias), f16 MFMA ----------------
// Staging via global_load_lds width=16 (m97 pattern): LDS dest lane-linear,
// XOR chunk swizzle applied to the SOURCE address; reads XOR the chunk index.
// MODE 0: outF fp32 row-major.  MODE 1: QKV scatter -> Q[B,H,T,D]*QKSCALE, K[B,H,T,D], V^T[B,H,D,T]
template <int MODE>
__global__ __launch_bounds__(256) void gemm_f16(const _Float16* __restrict__ A,
                                                const _Float16* __restrict__ Bt,
                                                const float* __restrict__ bias,
                                                float* __restrict__ outF,
                                                _Float16* __restrict__ oQ,
                                                _Float16* __restrict__ oK,
                                                _Float16* __restrict__ oV,
                                                int M, int N, int K) {
  __shared__ _Float16 As[128 * 64];
  __shared__ _Float16 Bs[128 * 64];
  const int m0 = blockIdx.y * 128, n0 = blockIdx.x * 128;
  const int tid = threadIdx.x;
  const int wave = tid >> 6, lane = tid & 63;
  const int wr = (wave >> 1) * 64, wc = (wave & 1) * 64;
  const int lrow = lane & 15, g = lane >> 4;

  // per-thread staging slot: L = i*256 + tid -> row = L>>3, chunk slot c = L&7
  // source chunk = c ^ (row&7); LDS dest = L*16 bytes (lane-linear within wave)
  const int row_ = tid >> 3, c_ = tid & 7;

  f4 acc[4][4];
  const f4 z4 = {0.f, 0.f, 0.f, 0.f};
#pragma unroll
  for (int m = 0; m < 4; ++m)
#pragma unroll
    for (int n = 0; n < 4; ++n) acc[m][n] = z4;

  for (int k0 = 0; k0 < K; k0 += 64) {
#pragma unroll
    for (int i = 0; i < 4; ++i) {
      int row = i * 32 + row_;                 // L = i*256 + tid, row = L>>3
      int cs = (c_ ^ (row & 7)) * 8;           // swizzled source chunk
      int ldst = (i * 256 + tid) * 8;          // LDS element offset (16B per thread)
      gload16(&A[(size_t)(m0 + row) * K + k0 + cs], &As[ldst]);
      gload16(&Bt[(size_t)(n0 + row) * K + k0 + cs], &Bs[ldst]);
    }
    __syncthreads();  // drains vmcnt -> tiles ready
#pragma unroll
    for (int ss = 0; ss < 2; ++ss) {
      h8 af[4], bf[4];
#pragma unroll
      for (int m = 0; m < 4; ++m) {
        int row = wr + m * 16 + lrow;
        af[m] = *(const h8*)&As[row * 64 + (((ss * 4 + g) ^ (row & 7)) * 8)];
      }
#pragma unroll
      for (int n = 0; n < 4; ++n) {
        int row = wc + n * 16 + lrow;
        bf[n] = *(const h8*)&Bs[row * 64 + (((ss * 4 + g) ^ (row & 7)) * 8)];
      }
      __builtin_amdgcn_s_setprio(1);
#pragma unroll
      for (int m = 0; m < 4; ++m)
#pragma unroll
        for (int n = 0; n < 4; ++n)
          acc[m][n] = __builtin_amdgcn_mfma_f32_16x16x32_f16(af[m], bf[n], acc[m][n], 0, 0, 0);
      __builtin_amdgcn_s_setprio(0);
    }
    __syncthreads();
  }

  // epilogue; C/D layout: col = lane&15, row = (lane>>4)*4 + r  [m89]
#pragma unroll
  for (int n = 0; n < 4; ++n) {
    const int gcol = n0 + wc + n * 16 + lrow;
    const float bv = bias ? bias[gcol] : 0.f;
    if (MODE == 1 && (gcol >> 10) == 2) {
      // V part: pack 4 r-consecutive t values into one 8B store (V^T is [B,H,D,T])
      const int c1 = gcol & 1023;
      const int hh = c1 >> 6, d = c1 & 63;
#pragma unroll
      for (int m = 0; m < 4; ++m) {
        const int grow = m0 + wr + m * 16 + g * 4;  // r=0 row; 4 consecutive t
        const int b = grow >> 11, t = grow & 2047;
        h4 pv;
#pragma unroll
        for (int r = 0; r < 4; ++r) pv[r] = (_Float16)(acc[m][n][r] + bv);
        *(h4*)&oV[(((size_t)(b * 16 + hh)) * 64 + d) * 2048 + t] = pv;
      }
    } else {
#pragma unroll
      for (int m = 0; m < 4; ++m) {
#pragma unroll
        for (int r = 0; r < 4; ++r) {
          const int grow = m0 + wr + m * 16 + g * 4 + r;
          float v = acc[m][n][r] + bv;
          if (MODE == 0) {
            outF[(size_t)grow * N + gcol] = v;
          } else {
            int part = gcol >> 10;
            int c1 = gcol & 1023;
            int hh = c1 >> 6, d = c1 & 63;
            int b = grow >> 11, t = grow & 2047;
            int bh = b * 16 + hh;
            if (part == 0)
              oQ[((size_t)bh * 2048 + t) * 64 + d] = (_Float16)(v * QKSCALE);
            else
              oK[((size_t)bh * 2048 + t) * 64 + d] = (_Float16)v;
          }
        }
      }
    }
  }
}

// ---------------- flash attention v6: paired q-tiles for uniform block work ----------
// Block = TWO q-tiles: (63-pi) then (pi). Total KV-iterations per block = 33 +- 0.5,
// UNIFORM across all 1024 blocks -> grid = 4 blocks/CU = exactly the VGPR-capped
// residency; no drain tail (r5: occupancy 20.8% from work variance).
// Within a tile: 4 waves split KV tiles (it = wave, wave+4, ...), merge via LDS.
// slab[wave] is P staging during the loop, then normalized f16 O partials.
// Defer-max (THR=8): fast-path iterations have zero cross-lane ops.
// NO launch-bounds occupancy hint (r3: forced cap -> 310MB scratch spill).
__global__ __launch_bounds__(256) void attn_kernel(const _Float16* __restrict__ Qg,
                                                   const _Float16* __restrict__ Kg,
                                                   const _Float16* __restrict__ Vtg,
                                                   _Float16* __restrict__ Og) {
  __shared__ _Float16 slab[4][32][72];  // P staging -> normalized O partials (f16)
  __shared__ float mlds[2][4][32];      // [0]=m, [1]=l per wave per q-row

  const int idx = blockIdx.x;  // 0..1023
  // XCD-affinity (%8 round-robin over bh)
  const int bh = (idx & 7) | (((idx >> 3) & 3) << 3);
  const int pi = idx >> 5;  // 0..31: this block owns q-tiles (63-pi) and (pi)

  const int wave = threadIdx.x >> 6, lane = threadIdx.x & 63;
  const int lrow = lane & 15, g = lane >> 4;
  const int b = bh >> 4, h = bh & 15;
  const _Float16* Q = Qg + (size_t)bh * 2048 * 64;
  const _Float16* K = Kg + (size_t)bh * 2048 * 64;
  const _Float16* Vt = Vtg + (size_t)bh * 64 * 2048;
  _Float16(*pw)[72] = slab[wave];
  const f4 z4 = {0.f, 0.f, 0.f, 0.f};

  for (int half = 0; half < 2; ++half) {
    const int qt2 = half == 0 ? 63 - pi : pi;
    const int q0 = qt2 * 32;

    h8 aq[2][2];
#pragma unroll
    for (int mt = 0; mt < 2; ++mt)
#pragma unroll
      for (int ss = 0; ss < 2; ++ss)
        aq[mt][ss] = *(const h8*)&Q[(q0 + mt * 16 + lrow) * 64 + ss * 32 + g * 8];

    f4 o[2][4];
#pragma unroll
    for (int mt = 0; mt < 2; ++mt)
#pragma unroll
      for (int dt = 0; dt < 4; ++dt) o[mt][dt] = z4;
    float mrow[2][4], lpart[2][4];
#pragma unroll
    for (int mt = 0; mt < 2; ++mt)
#pragma unroll
      for (int r = 0; r < 4; ++r) { mrow[mt][r] = -1e30f; lpart[mt][r] = 0.f; }

    const int NT = (qt2 >> 1) + 1;  // KV tiles of 64 covering rows [q0, q0+32)

    for (int it = wave; it < NT; it += 4) {
      const int kv0 = it * 64;
      // K fragment loads
      h8 kf[4][2];
#pragma unroll
      for (int ct = 0; ct < 4; ++ct)
#pragma unroll
        for (int ss = 0; ss < 2; ++ss)
          kf[ct][ss] = *(const h8*)&K[(kv0 + ct * 16 + lrow) * 64 + ss * 32 + g * 8];

      f4 s[2][4];
#pragma unroll
      for (int mt = 0; mt < 2; ++mt)
#pragma unroll
        for (int ct = 0; ct < 4; ++ct) s[mt][ct] = z4;
#pragma unroll
      for (int ss = 0; ss < 2; ++ss)
#pragma unroll
        for (int mt = 0; mt < 2; ++mt)
#pragma unroll
          for (int ct = 0; ct < 4; ++ct)
            s[mt][ct] = __builtin_amdgcn_mfma_f32_16x16x32_f16(aq[mt][ss], kf[ct][ss], s[mt][ct], 0, 0, 0);

      // V fragment loads: after QK (kf dead), before softmax (latency hides)
      h8 vf[4][2];
#pragma unroll
      for (int dt = 0; dt < 4; ++dt)
#pragma unroll
        for (int ss = 0; ss < 2; ++ss)
          vf[dt][ss] = *(const h8*)&Vt[(size_t)(dt * 16 + lrow) * 2048 + kv0 + ss * 32 + g * 8];

      if (it == NT - 1) {  // diagonal tile: causal mask
#pragma unroll
        for (int mt = 0; mt < 2; ++mt)
#pragma unroll
          for (int ct = 0; ct < 4; ++ct)
#pragma unroll
            for (int r = 0; r < 4; ++r)
              if (kv0 + ct * 16 + lrow > q0 + mt * 16 + g * 4 + r) s[mt][ct][r] = -1e30f;
      }

      // defer-max: in-lane partial maxima, full reduce only when THR exceeded
      float pm[2][4];
      bool need = false;
#pragma unroll
      for (int mt = 0; mt < 2; ++mt)
#pragma unroll
        for (int r = 0; r < 4; ++r) {
          pm[mt][r] = fmaxf(fmaxf(s[mt][0][r], s[mt][1][r]), fmaxf(s[mt][2][r], s[mt][3][r]));
          need = need || (pm[mt][r] > mrow[mt][r] + 8.f);
        }
      if (__any(need)) {  // slow path: full row max + rescale
#pragma unroll
        for (int mt = 0; mt < 2; ++mt)
#pragma unroll
          for (int r = 0; r < 4; ++r) {
            float m = pm[mt][r];
            m = fmaxf(m, __shfl_xor(m, 1));
            m = fmaxf(m, __shfl_xor(m, 2));
            m = fmaxf(m, __shfl_xor(m, 4));
            m = fmaxf(m, __shfl_xor(m, 8));
            float mn = fmaxf(mrow[mt][r], m);
            float fr = __builtin_amdgcn_exp2f(mrow[mt][r] - mn);
            mrow[mt][r] = mn;
            lpart[mt][r] *= fr;
#pragma unroll
            for (int dt = 0; dt < 4; ++dt) o[mt][dt][r] *= fr;
          }
      }
      // exp + lane-partial sum + P (C/D layout) -> LDS in A-frag layout
#pragma unroll
      for (int mt = 0; mt < 2; ++mt)
#pragma unroll
        for (int r = 0; r < 4; ++r) {
          float ps = 0.f;
#pragma unroll
          for (int ct = 0; ct < 4; ++ct) {
            float p = __builtin_amdgcn_exp2f(s[mt][ct][r] - mrow[mt][r]);
            ps += p;
            pw[mt * 16 + g * 4 + r][ct * 16 + lrow] = (_Float16)p;
          }
          lpart[mt][r] += ps;
        }

      h8 ap[2][2];
#pragma unroll
      for (int mt = 0; mt < 2; ++mt)
#pragma unroll
        for (int ss = 0; ss < 2; ++ss)
          ap[mt][ss] = *(const h8*)&pw[mt * 16 + lrow][ss * 32 + g * 8];

#pragma unroll
      for (int ss = 0; ss < 2; ++ss)
#pragma unroll
        for (int mt = 0; mt < 2; ++mt)
#pragma unroll
          for (int dt = 0; dt < 4; ++dt)
            o[mt][dt] = __builtin_amdgcn_mfma_f32_16x16x32_f16(ap[mt][ss], vf[dt][ss], o[mt][dt], 0, 0, 0);
    }

    // ---- reduce l partials across the 16-lane row group (once) ----
#pragma unroll
    for (int mt = 0; mt < 2; ++mt)
#pragma unroll
      for (int r = 0; r < 4; ++r) {
        float l = lpart[mt][r];
        l += __shfl_xor(l, 1);
        l += __shfl_xor(l, 2);
        l += __shfl_xor(l, 4);
        l += __shfl_xor(l, 8);
        lpart[mt][r] = l;
      }

    // ---- write per-wave partials: m,l + NORMALIZED o (f16) into slab ----
    if (lrow == 0) {
#pragma unroll
      for (int mt = 0; mt < 2; ++mt)
#pragma unroll
        for (int r = 0; r < 4; ++r) {
          mlds[0][wave][mt * 16 + g * 4 + r] = mrow[mt][r];
          mlds[1][wave][mt * 16 + g * 4 + r] = lpart[mt][r];
        }
    }
#pragma unroll
    for (int mt = 0; mt < 2; ++mt)
#pragma unroll
      for (int r = 0; r < 4; ++r) {
        float inv = lpart[mt][r] > 0.f ? 1.f / lpart[mt][r] : 0.f;
#pragma unroll
        for (int dt = 0; dt < 4; ++dt)
          pw[mt * 16 + g * 4 + r][dt * 16 + lrow] = (_Float16)(o[mt][dt][r] * inv);
      }
    __syncthreads();

    // ---- merge 4 waves & write O (f16 [B,T,C]); weights f_w = exp2(m_w - M) * l_w ----
    {
      const int ql = threadIdx.x >> 3;        // 0..31
      const int d0 = (threadIdx.x & 7) * 8;   // 0..56
      float m0 = mlds[0][0][ql], m1 = mlds[0][1][ql], m2 = mlds[0][2][ql], m3 = mlds[0][3][ql];
      float M = fmaxf(fmaxf(m0, m1), fmaxf(m2, m3));
      float f0 = __builtin_amdgcn_exp2f(m0 - M) * mlds[1][0][ql];
      float f1 = __builtin_amdgcn_exp2f(m1 - M) * mlds[1][1][ql];
      float f2 = __builtin_amdgcn_exp2f(m2 - M) * mlds[1][2][ql];
      float f3 = __builtin_amdgcn_exp2f(m3 - M) * mlds[1][3][ql];
      float inv = 1.f / (f0 + f1 + f2 + f3);
      h8 o0 = *(const h8*)&slab[0][ql][d0];
      h8 o1 = *(const h8*)&slab[1][ql][d0];
      h8 o2 = *(const h8*)&slab[2][ql][d0];
      h8 o3 = *(const h8*)&slab[3][ql][d0];
      h8 outv;
#pragma unroll
      for (int j = 0; j < 8; ++j) {
        float v = f0 * (float)o0[j] + f1 * (float)o1[j] + f2 * (float)o2[j] + f3 * (float)o3[j];
        outv[j] = (_Float16)(v * inv);
      }
      *(h8*)&Og[((size_t)b * 2048 + q0 + ql) * 1024 + h * 64 + d0] = outv;
    }
    if (half == 0) __syncthreads();  // protect slab/mlds reuse by second tile
  }
}

// ---------------- launch ----------------
extern "C" void kernel_launch(void* const* d_in, const int* in_sizes, int n_in,
                              void* d_out, int out_size, void* d_ws, size_t ws_size,
                              hipStream_t stream) {
  const float* x = (const float*)d_in[0];       // [2,2048,1024]
  const float* Wqkv = (const float*)d_in[1];    // [1024,3072]
  const float* bqkv = (const float*)d_in[2];    // [3072]
  const float* Wproj = (const float*)d_in[3];   // [1024,1024]
  const float* bproj = (const float*)d_in[4];   // [1024]
  float* out = (float*)d_out;                   // [2,2048,1024] fp32

  char* ws = (char*)d_ws;
  const size_t MB = 1u << 20;
  _Float16* xh     = (_Float16*)(ws + 0 * MB);   // 4M f16 = 8MB
  _Float16* wqkvt  = (_Float16*)(ws + 8 * MB);   // [3072][1024] = 6MB
  _Float16* wprojt = (_Float16*)(ws + 14 * MB);  // [1024][1024] = 2MB
  _Float16* qh     = (_Float16*)(ws + 16 * MB);  // [B,H,T,D] = 8MB (pre-scaled)
  _Float16* kh     = (_Float16*)(ws + 24 * MB);  // [B,H,T,D] = 8MB
  _Float16* vth    = (_Float16*)(ws + 32 * MB);  // [B,H,D,T] = 8MB
  _Float16* oh     = (_Float16*)(ws + 40 * MB);  // [B,T,C]   = 8MB

  cast_f16_kernel<<<2048, 256, 0, stream>>>(x, xh, 4194304);
  transp_cast_kernel<<<dim3(48, 16), 256, 0, stream>>>(Wqkv, wqkvt, 1024, 3072);
  transp_cast_kernel<<<dim3(16, 16), 256, 0, stream>>>(Wproj, wprojt, 1024, 1024);

  gemm_f16<1><<<dim3(24, 32), 256, 0, stream>>>(xh, wqkvt, bqkv, nullptr, qh, kh, vth,
                                                4096, 3072, 1024);
  attn_kernel<<<dim3(1024), 256, 0, stream>>>(qh, kh, vth, oh);
  gemm_f16<0><<<dim3(8, 32), 256, 0, stream>>>(oh, wprojt, bproj, out, nullptr, nullptr, nullptr,
                                               4096, 1024, 1024);
}

// Round 7
// 149.275 us; speedup vs baseline: 1.5047x; 1.0167x over previous
//
#include <hip/hip_runtime.h>

typedef __attribute__((ext_vector_type(8))) _Float16 h8;
typedef __attribute__((ext_vector_type(4))) _Float16 h4;
typedef __attribute__((ext_vector_type(2))) _Float16 h2;
typedef __attribute__((ext_vector_type(4))) float f4;
typedef __attribute__((ext_vector_type(16))) float f16v;

#define QKSCALE 0.18033688011112042f  // 2^-3 * log2(e): fold softmax scale + exp2 conversion into Q
#define Z16 {0.f,0.f,0.f,0.f,0.f,0.f,0.f,0.f,0.f,0.f,0.f,0.f,0.f,0.f,0.f,0.f}

// async global->LDS, 16B per lane (dest must be lane-linear; source may be per-lane swizzled)
__device__ __forceinline__ void gload16(const void* g, void* l) {
  __builtin_amdgcn_global_load_lds((const __attribute__((address_space(1))) void*)g,
                                   (__attribute__((address_space(3))) void*)l, 16, 0, 0);
}

__device__ __forceinline__ h2 pkh2(float a, float b) {
  return __builtin_bit_cast(h2, __builtin_amdgcn_cvt_pkrtz(a, b));
}
__device__ __forceinline__ h2 swap32_h2(h2 v) {
  return __builtin_bit_cast(h2, __shfl_xor(__builtin_bit_cast(int, v), 32));
}

// ---------------- cast x (fp32 -> f16) ----------------
__global__ __launch_bounds__(256) void cast_f16_kernel(const float* __restrict__ in,
                                                       _Float16* __restrict__ out, int n) {
  int i = (blockIdx.x * 256 + threadIdx.x) * 8;
  if (i >= n) return;
  const float4* p = (const float4*)(in + i);
  float4 a = p[0], b = p[1];
  h8 v;
  v[0] = (_Float16)a.x; v[1] = (_Float16)a.y; v[2] = (_Float16)a.z; v[3] = (_Float16)a.w;
  v[4] = (_Float16)b.x; v[5] = (_Float16)b.y; v[6] = (_Float16)b.z; v[7] = (_Float16)b.w;
  *(h8*)(out + i) = v;
}

// ---------------- transpose-cast W [K][N] fp32 -> Wt [N][K] f16 ----------------
__global__ __launch_bounds__(256) void transp_cast_kernel(const float* __restrict__ W,
                                                          _Float16* __restrict__ Wt, int K, int N) {
  __shared__ _Float16 tile[64][72];
  int k0 = blockIdx.y * 64, n0 = blockIdx.x * 64;
  int t = threadIdx.x;
#pragma unroll
  for (int i = 0; i < 16; ++i) {
    int idx = i * 256 + t;
    int kr = idx >> 6, nc = idx & 63;
    tile[kr][nc] = (_Float16)W[(size_t)(k0 + kr) * N + n0 + nc];
  }
  __syncthreads();
#pragma unroll
  for (int i = 0; i < 2; ++i) {
    int idx = i * 256 + t;
    int nr = idx >> 3, kc = (idx & 7) * 8;
    h8 v;
#pragma unroll
    for (int j = 0; j < 8; ++j) v[j] = tile[kc + j][nr];
    *(h8*)&Wt[(size_t)(n0 + nr) * K + k0 + kc] = v;
  }
}

// ---------------- GEMM: C[M,N] = A[M,K] * Bt[N,K]^T (+bias), f16 MFMA ----------------
// Staging via global_load_lds width=16 (m97 pattern): LDS dest lane-linear,
// XOR chunk swizzle applied to the SOURCE address; reads XOR the chunk index.
// MODE 0: outF fp32 row-major.  MODE 1: QKV scatter -> Q[B,H,T,D]*QKSCALE, K[B,H,T,D], V^T[B,H,D,T]
template <int MODE>
__global__ __launch_bounds__(256) void gemm_f16(const _Float16* __restrict__ A,
                                                const _Float16* __restrict__ Bt,
                                                const float* __restrict__ bias,
                                                float* __restrict__ outF,
                                                _Float16* __restrict__ oQ,
                                                _Float16* __restrict__ oK,
                                                _Float16* __restrict__ oV,
                                                int M, int N, int K) {
  __shared__ _Float16 As[128 * 64];
  __shared__ _Float16 Bs[128 * 64];
  const int m0 = blockIdx.y * 128, n0 = blockIdx.x * 128;
  const int tid = threadIdx.x;
  const int wave = tid >> 6, lane = tid & 63;
  const int wr = (wave >> 1) * 64, wc = (wave & 1) * 64;
  const int lrow = lane & 15, g = lane >> 4;

  const int row_ = tid >> 3, c_ = tid & 7;

  f4 acc[4][4];
  const f4 z4 = {0.f, 0.f, 0.f, 0.f};
#pragma unroll
  for (int m = 0; m < 4; ++m)
#pragma unroll
    for (int n = 0; n < 4; ++n) acc[m][n] = z4;

  for (int k0 = 0; k0 < K; k0 += 64) {
#pragma unroll
    for (int i = 0; i < 4; ++i) {
      int row = i * 32 + row_;
      int cs = (c_ ^ (row & 7)) * 8;
      int ldst = (i * 256 + tid) * 8;
      gload16(&A[(size_t)(m0 + row) * K + k0 + cs], &As[ldst]);
      gload16(&Bt[(size_t)(n0 + row) * K + k0 + cs], &Bs[ldst]);
    }
    __syncthreads();
#pragma unroll
    for (int ss = 0; ss < 2; ++ss) {
      h8 af[4], bf[4];
#pragma unroll
      for (int m = 0; m < 4; ++m) {
        int row = wr + m * 16 + lrow;
        af[m] = *(const h8*)&As[row * 64 + (((ss * 4 + g) ^ (row & 7)) * 8)];
      }
#pragma unroll
      for (int n = 0; n < 4; ++n) {
        int row = wc + n * 16 + lrow;
        bf[n] = *(const h8*)&Bs[row * 64 + (((ss * 4 + g) ^ (row & 7)) * 8)];
      }
      __builtin_amdgcn_s_setprio(1);
#pragma unroll
      for (int m = 0; m < 4; ++m)
#pragma unroll
        for (int n = 0; n < 4; ++n)
          acc[m][n] = __builtin_amdgcn_mfma_f32_16x16x32_f16(af[m], bf[n], acc[m][n], 0, 0, 0);
      __builtin_amdgcn_s_setprio(0);
    }
    __syncthreads();
  }

  // epilogue; C/D layout: col = lane&15, row = (lane>>4)*4 + r  [m89]
#pragma unroll
  for (int n = 0; n < 4; ++n) {
    const int gcol = n0 + wc + n * 16 + lrow;
    const float bv = bias ? bias[gcol] : 0.f;
    if (MODE == 1 && (gcol >> 10) == 2) {
      const int c1 = gcol & 1023;
      const int hh = c1 >> 6, d = c1 & 63;
#pragma unroll
      for (int m = 0; m < 4; ++m) {
        const int grow = m0 + wr + m * 16 + g * 4;
        const int b = grow >> 11, t = grow & 2047;
        h4 pv;
#pragma unroll
        for (int r = 0; r < 4; ++r) pv[r] = (_Float16)(acc[m][n][r] + bv);
        *(h4*)&oV[(((size_t)(b * 16 + hh)) * 64 + d) * 2048 + t] = pv;
      }
    } else {
#pragma unroll
      for (int m = 0; m < 4; ++m) {
#pragma unroll
        for (int r = 0; r < 4; ++r) {
          const int grow = m0 + wr + m * 16 + g * 4 + r;
          float v = acc[m][n][r] + bv;
          if (MODE == 0) {
            outF[(size_t)grow * N + gcol] = v;
          } else {
            int part = gcol >> 10;
            int c1 = gcol & 1023;
            int hh = c1 >> 6, d = c1 & 63;
            int b = grow >> 11, t = grow & 2047;
            int bh = b * 16 + hh;
            if (part == 0)
              oQ[((size_t)bh * 2048 + t) * 64 + d] = (_Float16)(v * QKSCALE);
            else
              oK[((size_t)bh * 2048 + t) * 64 + d] = (_Float16)v;
          }
        }
      }
    }
  }
}

// ---------------- flash attention v7: 32x32 swapped-QK^T, in-register softmax ----------
// S^T = K.Q^T via mfma_32x32x16 (A=K rows kk, B=Q^T cols q): lane owns q=lane&31.
// Row max = in-lane 31-fmax + one shfl_xor(32). m,l = lane-local scalars.
// P -> PV A-frags in registers: cvt_pkrtz pairs + 8 shfl_xor(32) per iter (T12).
// No LDS P round-trip, no 16-lane shuffle reductions. C/D map (m74/m101):
// col=lane&31, row=(reg&3)+8*(reg>>2)+4*(lane>>5). A/B frag: row/col=lane&31,
// k=(lane>>5)*8+j (mirrors the verified 16x16 pattern).
// Split-KV across 4 waves + paired q-tiles (63-pi, pi) kept from r6.
__global__ __launch_bounds__(256) void attn_kernel(const _Float16* __restrict__ Qg,
                                                   const _Float16* __restrict__ Kg,
                                                   const _Float16* __restrict__ Vtg,
                                                   _Float16* __restrict__ Og) {
  __shared__ _Float16 slab[4][32][72];  // normalized f16 O partials per wave
  __shared__ float mlds[2][4][32];      // [0]=m, [1]=l per wave per q-row

  const int idx = blockIdx.x;  // 0..1023
  const int bh = (idx & 7) | (((idx >> 3) & 3) << 3);
  const int pi = idx >> 5;  // 0..31: q-tiles (63-pi) and (pi)

  const int wave = threadIdx.x >> 6, lane = threadIdx.x & 63;
  const int ln = lane & 31, hi = lane >> 5;
  const int b = bh >> 4, h = bh & 15;
  const _Float16* Q = Qg + (size_t)bh * 2048 * 64;
  const _Float16* K = Kg + (size_t)bh * 2048 * 64;
  const _Float16* Vt = Vtg + (size_t)bh * 64 * 2048;
  _Float16(*pw)[72] = slab[wave];

  for (int half = 0; half < 2; ++half) {
    const int qt2 = half == 0 ? 63 - pi : pi;
    const int q0 = qt2 * 32;

    // Q^T B-frags: col q=ln, k-elems d = ds*16 + hi*8 + j
    h8 qf[4];
#pragma unroll
    for (int ds = 0; ds < 4; ++ds)
      qf[ds] = *(const h8*)&Q[(q0 + ln) * 64 + ds * 16 + hi * 8];

    f16v o0 = Z16, o1 = Z16;
    float m = -1e30f, l = 0.f;
    const int NT = (qt2 >> 1) + 1;  // KV tiles of 64 covering rows [q0, q0+32)

    for (int it = wave; it < NT; it += 4) {
      const int kv0 = it * 64;
      // K A-frags: rows kk = kt*32 + ln, k-elems d = ds*16 + hi*8 + j
      h8 kf[2][4];
#pragma unroll
      for (int kt = 0; kt < 2; ++kt)
#pragma unroll
        for (int ds = 0; ds < 4; ++ds)
          kf[kt][ds] = *(const h8*)&K[(kv0 + kt * 32 + ln) * 64 + ds * 16 + hi * 8];

      f16v s0 = Z16, s1 = Z16;
      __builtin_amdgcn_s_setprio(1);
#pragma unroll
      for (int ds = 0; ds < 4; ++ds)
        s0 = __builtin_amdgcn_mfma_f32_32x32x16_f16(kf[0][ds], qf[ds], s0, 0, 0, 0);
#pragma unroll
      for (int ds = 0; ds < 4; ++ds)
        s1 = __builtin_amdgcn_mfma_f32_32x32x16_f16(kf[1][ds], qf[ds], s1, 0, 0, 0);
      __builtin_amdgcn_s_setprio(0);

      // V^T B-frags (issued early; latency hides under softmax+pack)
      h8 vf[2][4];  // [dtile][kslot]
#pragma unroll
      for (int dt = 0; dt < 2; ++dt)
#pragma unroll
        for (int ks = 0; ks < 4; ++ks)
          vf[dt][ks] = *(const h8*)&Vt[(size_t)(dt * 32 + ln) * 2048 + kv0 + ks * 16 + hi * 8];

      if (it == NT - 1) {  // diagonal tile: causal mask (k > q)
        const int qg = q0 + ln;
#pragma unroll
        for (int reg = 0; reg < 16; ++reg) {
          const int crow = (reg & 3) + 8 * (reg >> 2) + 4 * hi;
          if (kv0 + crow > qg) s0[reg] = -1e30f;
          if (kv0 + 32 + crow > qg) s1[reg] = -1e30f;
        }
      }

      // in-lane row max over 32 kk + one cross-half exchange
      float pm = fmaxf(s0[0], s1[0]);
#pragma unroll
      for (int reg = 1; reg < 16; ++reg) pm = fmaxf(pm, fmaxf(s0[reg], s1[reg]));
      pm = fmaxf(pm, __shfl_xor(pm, 32));

      if (__any(pm > m + 8.f)) {  // defer-max slow path (first tile, rare after)
        const float mn = fmaxf(m, pm);
        const float fr = __builtin_amdgcn_exp2f(m - mn);
        m = mn;
        l *= fr;
#pragma unroll
        for (int reg = 0; reg < 16; ++reg) {
          const float frr = __shfl(fr, (reg & 3) + 8 * (reg >> 2) + 4 * hi);
          o0[reg] *= frr;
          o1[reg] *= frr;
        }
      }

      // exp (lane-local m!) + lane-partial l
      float ls = 0.f;
#pragma unroll
      for (int reg = 0; reg < 16; ++reg) {
        s0[reg] = __builtin_amdgcn_exp2f(s0[reg] - m);
        s1[reg] = __builtin_amdgcn_exp2f(s1[reg] - m);
        ls += s0[reg] + s1[reg];
      }
      l += ls;

      // pack P pairs: Pk[R][pr] = pk(s[4R+2pr], s[4R+2pr+1])
      h2 Pk0[4][2], Pk1[4][2];
#pragma unroll
      for (int R = 0; R < 4; ++R)
#pragma unroll
        for (int pr = 0; pr < 2; ++pr) {
          Pk0[R][pr] = pkh2(s0[4 * R + 2 * pr], s0[4 * R + 2 * pr + 1]);
          Pk1[R][pr] = pkh2(s1[4 * R + 2 * pr], s1[4 * R + 2 * pr + 1]);
        }

      // assemble PV A-frags (8 f16 = kk ks*16+hi*8+j) + accumulate
      __builtin_amdgcn_s_setprio(1);
#pragma unroll
      for (int ks = 0; ks < 4; ++ks) {
        const int Rb = 2 * (ks & 1);
        h2 a0p0 = (ks >> 1) ? Pk1[Rb][0] : Pk0[Rb][0];
        h2 a0p1 = (ks >> 1) ? Pk1[Rb][1] : Pk0[Rb][1];
        h2 a1p0 = (ks >> 1) ? Pk1[Rb + 1][0] : Pk0[Rb + 1][0];
        h2 a1p1 = (ks >> 1) ? Pk1[Rb + 1][1] : Pk0[Rb + 1][1];
        h2 loc0 = hi ? a1p0 : a0p0;  // my half's contribution (R = Rb+hi)
        h2 loc1 = hi ? a1p1 : a0p1;
        h2 snd0 = hi ? a0p0 : a1p0;  // what the other half needs from me
        h2 snd1 = hi ? a0p1 : a1p1;
        h2 rem0 = swap32_h2(snd0);
        h2 rem1 = swap32_h2(snd1);
        h2 w0 = hi ? rem0 : loc0;  // j=0,1 come from half 0
        h2 w1 = hi ? rem1 : loc1;  // j=2,3
        h2 w2 = hi ? loc0 : rem0;  // j=4,5 come from half 1
        h2 w3 = hi ? loc1 : rem1;  // j=6,7
        h8 pa;
        pa[0] = w0[0]; pa[1] = w0[1]; pa[2] = w1[0]; pa[3] = w1[1];
        pa[4] = w2[0]; pa[5] = w2[1]; pa[6] = w3[0]; pa[7] = w3[1];
        o0 = __builtin_amdgcn_mfma_f32_32x32x16_f16(pa, vf[0][ks], o0, 0, 0, 0);
        o1 = __builtin_amdgcn_mfma_f32_32x32x16_f16(pa, vf[1][ks], o1, 0, 0, 0);
      }
      __builtin_amdgcn_s_setprio(0);
    }

    // ---- finalize l; write per-wave partials (normalized f16 O + m,l) ----
    const float l_all = l + __shfl_xor(l, 32);
    if (hi == 0) {
      mlds[0][wave][ln] = m;
      mlds[1][wave][ln] = l_all;
    }
#pragma unroll
    for (int reg = 0; reg < 16; ++reg) {
      const int crow = (reg & 3) + 8 * (reg >> 2) + 4 * hi;
      const float li = __shfl(l_all, crow);
      const float inv = li > 0.f ? 1.f / li : 0.f;
      pw[crow][ln] = (_Float16)(o0[reg] * inv);
      pw[crow][32 + ln] = (_Float16)(o1[reg] * inv);
    }
    __syncthreads();

    // ---- merge 4 waves & write O (f16 [B,T,C]); weights f_w = exp2(m_w - M) * l_w ----
    {
      const int ql = threadIdx.x >> 3;        // 0..31
      const int d0 = (threadIdx.x & 7) * 8;   // 0..56
      float m0 = mlds[0][0][ql], m1 = mlds[0][1][ql], m2 = mlds[0][2][ql], m3 = mlds[0][3][ql];
      float M = fmaxf(fmaxf(m0, m1), fmaxf(m2, m3));
      float f0 = __builtin_amdgcn_exp2f(m0 - M) * mlds[1][0][ql];
      float f1 = __builtin_amdgcn_exp2f(m1 - M) * mlds[1][1][ql];
      float f2 = __builtin_amdgcn_exp2f(m2 - M) * mlds[1][2][ql];
      float f3 = __builtin_amdgcn_exp2f(m3 - M) * mlds[1][3][ql];
      float inv = 1.f / (f0 + f1 + f2 + f3);
      h8 o0v = *(const h8*)&slab[0][ql][d0];
      h8 o1v = *(const h8*)&slab[1][ql][d0];
      h8 o2v = *(const h8*)&slab[2][ql][d0];
      h8 o3v = *(const h8*)&slab[3][ql][d0];
      h8 outv;
#pragma unroll
      for (int j = 0; j < 8; ++j) {
        float v = f0 * (float)o0v[j] + f1 * (float)o1v[j] + f2 * (float)o2v[j] + f3 * (float)o3v[j];
        outv[j] = (_Float16)(v * inv);
      }
      *(h8*)&Og[((size_t)b * 2048 + q0 + ql) * 1024 + h * 64 + d0] = outv;
    }
    if (half == 0) __syncthreads();  // protect slab/mlds reuse by second tile
  }
}

// ---------------- launch ----------------
extern "C" void kernel_launch(void* const* d_in, const int* in_sizes, int n_in,
                              void* d_out, int out_size, void* d_ws, size_t ws_size,
                              hipStream_t stream) {
  const float* x = (const float*)d_in[0];       // [2,2048,1024]
  const float* Wqkv = (const float*)d_in[1];    // [1024,3072]
  const float* bqkv = (const float*)d_in[2];    // [3072]
  const float* Wproj = (const float*)d_in[3];   // [1024,1024]
  const float* bproj = (const float*)d_in[4];   // [1024]
  float* out = (float*)d_out;                   // [2,2048,1024] fp32

  char* ws = (char*)d_ws;
  const size_t MB = 1u << 20;
  _Float16* xh     = (_Float16*)(ws + 0 * MB);   // 4M f16 = 8MB
  _Float16* wqkvt  = (_Float16*)(ws + 8 * MB);   // [3072][1024] = 6MB
  _Float16* wprojt = (_Float16*)(ws + 14 * MB);  // [1024][1024] = 2MB
  _Float16* qh     = (_Float16*)(ws + 16 * MB);  // [B,H,T,D] = 8MB (pre-scaled)
  _Float16* kh     = (_Float16*)(ws + 24 * MB);  // [B,H,T,D] = 8MB
  _Float16* vth    = (_Float16*)(ws + 32 * MB);  // [B,H,D,T] = 8MB
  _Float16* oh     = (_Float16*)(ws + 40 * MB);  // [B,T,C]   = 8MB

  cast_f16_kernel<<<2048, 256, 0, stream>>>(x, xh, 4194304);
  transp_cast_kernel<<<dim3(48, 16), 256, 0, stream>>>(Wqkv, wqkvt, 1024, 3072);
  transp_cast_kernel<<<dim3(16, 16), 256, 0, stream>>>(Wproj, wprojt, 1024, 1024);

  gemm_f16<1><<<dim3(24, 32), 256, 0, stream>>>(xh, wqkvt, bqkv, nullptr, qh, kh, vth,
                                                4096, 3072, 1024);
  attn_kernel<<<dim3(1024), 256, 0, stream>>>(qh, kh, vth, oh);
  gemm_f16<0><<<dim3(8, 32), 256, 0, stream>>>(oh, wprojt, bproj, out, nullptr, nullptr, nullptr,
                                               4096, 1024, 1024);
}

// Round 8
// 145.503 us; speedup vs baseline: 1.5437x; 1.0259x over previous
//
#include <hip/hip_runtime.h>

typedef __attribute__((ext_vector_type(8))) _Float16 h8;
typedef __attribute__((ext_vector_type(4))) _Float16 h4;
typedef __attribute__((ext_vector_type(2))) _Float16 h2;
typedef __attribute__((ext_vector_type(4))) float f4;
typedef __attribute__((ext_vector_type(16))) float f16v;

#define QKSCALE 0.18033688011112042f  // 2^-3 * log2(e): fold softmax scale + exp2 conversion into Q
#define Z16 {0.f,0.f,0.f,0.f,0.f,0.f,0.f,0.f,0.f,0.f,0.f,0.f,0.f,0.f,0.f,0.f}

// async global->LDS, 16B per lane (dest must be lane-linear; source may be per-lane swizzled)
__device__ __forceinline__ void gload16(const void* g, void* l) {
  __builtin_amdgcn_global_load_lds((const __attribute__((address_space(1))) void*)g,
                                   (__attribute__((address_space(3))) void*)l, 16, 0, 0);
}

__device__ __forceinline__ h2 pkh2(float a, float b) {
  return __builtin_bit_cast(h2, __builtin_amdgcn_cvt_pkrtz(a, b));
}
__device__ __forceinline__ h2 swap32_h2(h2 v) {
  return __builtin_bit_cast(h2, __shfl_xor(__builtin_bit_cast(int, v), 32));
}

// ---------------- cast x (fp32 -> f16) ----------------
__global__ __launch_bounds__(256) void cast_f16_kernel(const float* __restrict__ in,
                                                       _Float16* __restrict__ out, int n) {
  int i = (blockIdx.x * 256 + threadIdx.x) * 8;
  if (i >= n) return;
  const float4* p = (const float4*)(in + i);
  float4 a = p[0], b = p[1];
  h8 v;
  v[0] = (_Float16)a.x; v[1] = (_Float16)a.y; v[2] = (_Float16)a.z; v[3] = (_Float16)a.w;
  v[4] = (_Float16)b.x; v[5] = (_Float16)b.y; v[6] = (_Float16)b.z; v[7] = (_Float16)b.w;
  *(h8*)(out + i) = v;
}

// ---------------- transpose-cast W [K][N] fp32 -> Wt [N][K] f16 ----------------
__global__ __launch_bounds__(256) void transp_cast_kernel(const float* __restrict__ W,
                                                          _Float16* __restrict__ Wt, int K, int N) {
  __shared__ _Float16 tile[64][72];
  int k0 = blockIdx.y * 64, n0 = blockIdx.x * 64;
  int t = threadIdx.x;
#pragma unroll
  for (int i = 0; i < 16; ++i) {
    int idx = i * 256 + t;
    int kr = idx >> 6, nc = idx & 63;
    tile[kr][nc] = (_Float16)W[(size_t)(k0 + kr) * N + n0 + nc];
  }
  __syncthreads();
#pragma unroll
  for (int i = 0; i < 2; ++i) {
    int idx = i * 256 + t;
    int nr = idx >> 3, kc = (idx & 7) * 8;
    h8 v;
#pragma unroll
    for (int j = 0; j < 8; ++j) v[j] = tile[kc + j][nr];
    *(h8*)&Wt[(size_t)(n0 + nr) * K + k0 + kc] = v;
  }
}

// ---------------- GEMM: C[M,N] = A[M,K] * Bt[N,K]^T (+bias), f16 MFMA ----------------
// Staging via global_load_lds width=16 (m97 pattern): LDS dest lane-linear,
// XOR chunk swizzle applied to the SOURCE address; reads XOR the chunk index.
// MODE 0: outF fp32 row-major.  MODE 1: QKV scatter -> Q[B,H,T,D]*QKSCALE, K[B,H,T,D], V^T[B,H,D,T]
template <int MODE>
__global__ __launch_bounds__(256) void gemm_f16(const _Float16* __restrict__ A,
                                                const _Float16* __restrict__ Bt,
                                                const float* __restrict__ bias,
                                                float* __restrict__ outF,
                                                _Float16* __restrict__ oQ,
                                                _Float16* __restrict__ oK,
                                                _Float16* __restrict__ oV,
                                                int M, int N, int K) {
  __shared__ _Float16 As[128 * 64];
  __shared__ _Float16 Bs[128 * 64];
  const int m0 = blockIdx.y * 128, n0 = blockIdx.x * 128;
  const int tid = threadIdx.x;
  const int wave = tid >> 6, lane = tid & 63;
  const int wr = (wave >> 1) * 64, wc = (wave & 1) * 64;
  const int lrow = lane & 15, g = lane >> 4;

  const int row_ = tid >> 3, c_ = tid & 7;

  f4 acc[4][4];
  const f4 z4 = {0.f, 0.f, 0.f, 0.f};
#pragma unroll
  for (int m = 0; m < 4; ++m)
#pragma unroll
    for (int n = 0; n < 4; ++n) acc[m][n] = z4;

  for (int k0 = 0; k0 < K; k0 += 64) {
#pragma unroll
    for (int i = 0; i < 4; ++i) {
      int row = i * 32 + row_;
      int cs = (c_ ^ (row & 7)) * 8;
      int ldst = (i * 256 + tid) * 8;
      gload16(&A[(size_t)(m0 + row) * K + k0 + cs], &As[ldst]);
      gload16(&Bt[(size_t)(n0 + row) * K + k0 + cs], &Bs[ldst]);
    }
    __syncthreads();
#pragma unroll
    for (int ss = 0; ss < 2; ++ss) {
      h8 af[4], bf[4];
#pragma unroll
      for (int m = 0; m < 4; ++m) {
        int row = wr + m * 16 + lrow;
        af[m] = *(const h8*)&As[row * 64 + (((ss * 4 + g) ^ (row & 7)) * 8)];
      }
#pragma unroll
      for (int n = 0; n < 4; ++n) {
        int row = wc + n * 16 + lrow;
        bf[n] = *(const h8*)&Bs[row * 64 + (((ss * 4 + g) ^ (row & 7)) * 8)];
      }
      __builtin_amdgcn_s_setprio(1);
#pragma unroll
      for (int m = 0; m < 4; ++m)
#pragma unroll
        for (int n = 0; n < 4; ++n)
          acc[m][n] = __builtin_amdgcn_mfma_f32_16x16x32_f16(af[m], bf[n], acc[m][n], 0, 0, 0);
      __builtin_amdgcn_s_setprio(0);
    }
    __syncthreads();
  }

  // epilogue; C/D layout: col = lane&15, row = (lane>>4)*4 + r  [m89]
#pragma unroll
  for (int n = 0; n < 4; ++n) {
    const int gcol = n0 + wc + n * 16 + lrow;
    const float bv = bias ? bias[gcol] : 0.f;
    if (MODE == 1 && (gcol >> 10) == 2) {
      const int c1 = gcol & 1023;
      const int hh = c1 >> 6, d = c1 & 63;
#pragma unroll
      for (int m = 0; m < 4; ++m) {
        const int grow = m0 + wr + m * 16 + g * 4;
        const int b = grow >> 11, t = grow & 2047;
        h4 pv;
#pragma unroll
        for (int r = 0; r < 4; ++r) pv[r] = (_Float16)(acc[m][n][r] + bv);
        *(h4*)&oV[(((size_t)(b * 16 + hh)) * 64 + d) * 2048 + t] = pv;
      }
    } else {
#pragma unroll
      for (int m = 0; m < 4; ++m) {
#pragma unroll
        for (int r = 0; r < 4; ++r) {
          const int grow = m0 + wr + m * 16 + g * 4 + r;
          float v = acc[m][n][r] + bv;
          if (MODE == 0) {
            outF[(size_t)grow * N + gcol] = v;
          } else {
            int part = gcol >> 10;
            int c1 = gcol & 1023;
            int hh = c1 >> 6, d = c1 & 63;
            int b = grow >> 11, t = grow & 2047;
            int bh = b * 16 + hh;
            if (part == 0)
              oQ[((size_t)bh * 2048 + t) * 64 + d] = (_Float16)(v * QKSCALE);
            else
              oK[((size_t)bh * 2048 + t) * 64 + d] = (_Float16)v;
          }
        }
      }
    }
  }
}

// ---------------- flash attention v8: KVBLK=32, lean registers for 4 waves/SIMD ----------
// r1-r7 all ran at 2 waves/SIMD (arch VGPR+AGPR total ~190-250, m69 cliff at 128).
// This version halves per-iteration state: single s (16), kf[4] (16), vf[2][2] (16),
// Pk (8); persistent qf (16) + o0/o1 (32). Target arch total <=128 -> 4 waves/SIMD.
// Swapped S^T = K.Q^T (lane owns q=ln), in-reg softmax, cvt_pkrtz+swap32 P assembly.
// C/D map: col=lane&31, row=(reg&3)+8*(reg>>2)+4*(lane>>5). Split-KV 4 waves,
// paired q-tiles (63-pi, pi). NO launch_bounds (r3: forcing caused 310MB spill).
__global__ void attn_kernel(const _Float16* __restrict__ Qg,
                            const _Float16* __restrict__ Kg,
                            const _Float16* __restrict__ Vtg,
                            _Float16* __restrict__ Og) {
  __shared__ _Float16 slab[4][32][72];  // normalized f16 O partials per wave
  __shared__ float mlds[2][4][32];      // [0]=m, [1]=l per wave per q-row

  const int idx = blockIdx.x;  // 0..1023
  const int bh = (idx & 7) | (((idx >> 3) & 3) << 3);
  const int pi = idx >> 5;  // 0..31: q-tiles (63-pi) and (pi)

  const int wave = threadIdx.x >> 6, lane = threadIdx.x & 63;
  const int ln = lane & 31, hi = lane >> 5;
  const int b = bh >> 4, h = bh & 15;
  const _Float16* Q = Qg + (size_t)bh * 2048 * 64;
  const _Float16* K = Kg + (size_t)bh * 2048 * 64;
  const _Float16* Vt = Vtg + (size_t)bh * 64 * 2048;
  _Float16(*pw)[72] = slab[wave];

  for (int half = 0; half < 2; ++half) {
    const int qt2 = half == 0 ? 63 - pi : pi;
    const int q0 = qt2 * 32;

    // Q^T B-frags: col q=ln, k-elems d = ds*16 + hi*8 + j
    h8 qf[4];
#pragma unroll
    for (int ds = 0; ds < 4; ++ds)
      qf[ds] = *(const h8*)&Q[(q0 + ln) * 64 + ds * 16 + hi * 8];

    f16v o0 = Z16, o1 = Z16;
    float m = -1e30f, l = 0.f;
    const int NT = qt2 + 1;  // KV tiles of 32 covering rows [q0, q0+32)

    for (int it = wave; it < NT; it += 4) {
      const int kv0 = it * 32;
      // K A-frags: rows kk = ln, k-elems d = ds*16 + hi*8 + j
      h8 kf[4];
#pragma unroll
      for (int ds = 0; ds < 4; ++ds)
        kf[ds] = *(const h8*)&K[(kv0 + ln) * 64 + ds * 16 + hi * 8];

      f16v s = Z16;
      __builtin_amdgcn_s_setprio(1);
#pragma unroll
      for (int ds = 0; ds < 4; ++ds)
        s = __builtin_amdgcn_mfma_f32_32x32x16_f16(kf[ds], qf[ds], s, 0, 0, 0);
      __builtin_amdgcn_s_setprio(0);

      // V^T B-frags (issued after QK: kf dead; latency hides under softmax+pack)
      h8 vf[2][2];  // [dtile][kslot]
#pragma unroll
      for (int dt = 0; dt < 2; ++dt)
#pragma unroll
        for (int ks = 0; ks < 2; ++ks)
          vf[dt][ks] = *(const h8*)&Vt[(size_t)(dt * 32 + ln) * 2048 + kv0 + ks * 16 + hi * 8];

      if (it == NT - 1) {  // diagonal tile (kv0 == q0): mask kk=crow > q=ln
#pragma unroll
        for (int reg = 0; reg < 16; ++reg) {
          const int crow = (reg & 3) + 8 * (reg >> 2) + 4 * hi;
          if (crow > ln) s[reg] = -1e30f;
        }
      }

      // in-lane row max over 16 regs + one cross-half exchange
      float pm = s[0];
#pragma unroll
      for (int reg = 1; reg < 16; ++reg) pm = fmaxf(pm, s[reg]);
      pm = fmaxf(pm, __shfl_xor(pm, 32));

      if (__any(pm > m + 8.f)) {  // defer-max slow path (first tile, rare after)
        const float mn = fmaxf(m, pm);
        const float fr = __builtin_amdgcn_exp2f(m - mn);
        m = mn;
        l *= fr;
#pragma unroll
        for (int reg = 0; reg < 16; ++reg) {
          const float frr = __shfl(fr, (reg & 3) + 8 * (reg >> 2) + 4 * hi);
          o0[reg] *= frr;
          o1[reg] *= frr;
        }
      }

      // exp (lane-local m) + lane-partial l
      float ls = 0.f;
#pragma unroll
      for (int reg = 0; reg < 16; ++reg) {
        s[reg] = __builtin_amdgcn_exp2f(s[reg] - m);
        ls += s[reg];
      }
      l += ls;

      // pack P pairs: Pk[R][pr] = pk(s[4R+2pr], s[4R+2pr+1])
      h2 Pk[4][2];
#pragma unroll
      for (int R = 0; R < 4; ++R)
#pragma unroll
        for (int pr = 0; pr < 2; ++pr)
          Pk[R][pr] = pkh2(s[4 * R + 2 * pr], s[4 * R + 2 * pr + 1]);

      // assemble PV A-frags (8 f16 = kk ks*16+hi*8+j) + accumulate
      __builtin_amdgcn_s_setprio(1);
#pragma unroll
      for (int ks = 0; ks < 2; ++ks) {
        const int Rb = 2 * ks;
        h2 a0p0 = Pk[Rb][0], a0p1 = Pk[Rb][1];
        h2 a1p0 = Pk[Rb + 1][0], a1p1 = Pk[Rb + 1][1];
        h2 loc0 = hi ? a1p0 : a0p0;  // my half's contribution (R = Rb+hi)
        h2 loc1 = hi ? a1p1 : a0p1;
        h2 snd0 = hi ? a0p0 : a1p0;  // what the other half needs from me
        h2 snd1 = hi ? a0p1 : a1p1;
        h2 rem0 = swap32_h2(snd0);
        h2 rem1 = swap32_h2(snd1);
        h2 w0 = hi ? rem0 : loc0;  // j=0,1 come from half 0
        h2 w1 = hi ? rem1 : loc1;  // j=2,3
        h2 w2 = hi ? loc0 : rem0;  // j=4,5 come from half 1
        h2 w3 = hi ? loc1 : rem1;  // j=6,7
        h8 pa;
        pa[0] = w0[0]; pa[1] = w0[1]; pa[2] = w1[0]; pa[3] = w1[1];
        pa[4] = w2[0]; pa[5] = w2[1]; pa[6] = w3[0]; pa[7] = w3[1];
        o0 = __builtin_amdgcn_mfma_f32_32x32x16_f16(pa, vf[0][ks], o0, 0, 0, 0);
        o1 = __builtin_amdgcn_mfma_f32_32x32x16_f16(pa, vf[1][ks], o1, 0, 0, 0);
      }
      __builtin_amdgcn_s_setprio(0);
    }

    // ---- finalize l; write per-wave partials (normalized f16 O + m,l) ----
    const float l_all = l + __shfl_xor(l, 32);
    if (hi == 0) {
      mlds[0][wave][ln] = m;
      mlds[1][wave][ln] = l_all;
    }
#pragma unroll
    for (int reg = 0; reg < 16; ++reg) {
      const int crow = (reg & 3) + 8 * (reg >> 2) + 4 * hi;
      const float li = __shfl(l_all, crow);
      const float inv = li > 0.f ? 1.f / li : 0.f;
      pw[crow][ln] = (_Float16)(o0[reg] * inv);
      pw[crow][32 + ln] = (_Float16)(o1[reg] * inv);
    }
    __syncthreads();

    // ---- merge 4 waves & write O (f16 [B,T,C]); weights f_w = exp2(m_w - M) * l_w ----
    {
      const int ql = threadIdx.x >> 3;        // 0..31
      const int d0 = (threadIdx.x & 7) * 8;   // 0..56
      float m0 = mlds[0][0][ql], m1 = mlds[0][1][ql], m2 = mlds[0][2][ql], m3 = mlds[0][3][ql];
      float M = fmaxf(fmaxf(m0, m1), fmaxf(m2, m3));
      float f0 = __builtin_amdgcn_exp2f(m0 - M) * mlds[1][0][ql];
      float f1 = __builtin_amdgcn_exp2f(m1 - M) * mlds[1][1][ql];
      float f2 = __builtin_amdgcn_exp2f(m2 - M) * mlds[1][2][ql];
      float f3 = __builtin_amdgcn_exp2f(m3 - M) * mlds[1][3][ql];
      float inv = 1.f / (f0 + f1 + f2 + f3);
      h8 o0v = *(const h8*)&slab[0][ql][d0];
      h8 o1v = *(const h8*)&slab[1][ql][d0];
      h8 o2v = *(const h8*)&slab[2][ql][d0];
      h8 o3v = *(const h8*)&slab[3][ql][d0];
      h8 outv;
#pragma unroll
      for (int j = 0; j < 8; ++j) {
        float v = f0 * (float)o0v[j] + f1 * (float)o1v[j] + f2 * (float)o2v[j] + f3 * (float)o3v[j];
        outv[j] = (_Float16)(v * inv);
      }
      *(h8*)&Og[((size_t)b * 2048 + q0 + ql) * 1024 + h * 64 + d0] = outv;
    }
    if (half == 0) __syncthreads();  // protect slab/mlds reuse by second tile
  }
}

// ---------------- launch ----------------
extern "C" void kernel_launch(void* const* d_in, const int* in_sizes, int n_in,
                              void* d_out, int out_size, void* d_ws, size_t ws_size,
                              hipStream_t stream) {
  const float* x = (const float*)d_in[0];       // [2,2048,1024]
  const float* Wqkv = (const float*)d_in[1];    // [1024,3072]
  const float* bqkv = (const float*)d_in[2];    // [3072]
  const float* Wproj = (const float*)d_in[3];   // [1024,1024]
  const float* bproj = (const float*)d_in[4];   // [1024]
  float* out = (float*)d_out;                   // [2,2048,1024] fp32

  char* ws = (char*)d_ws;
  const size_t MB = 1u << 20;
  _Float16* xh     = (_Float16*)(ws + 0 * MB);   // 4M f16 = 8MB
  _Float16* wqkvt  = (_Float16*)(ws + 8 * MB);   // [3072][1024] = 6MB
  _Float16* wprojt = (_Float16*)(ws + 14 * MB);  // [1024][1024] = 2MB
  _Float16* qh     = (_Float16*)(ws + 16 * MB);  // [B,H,T,D] = 8MB (pre-scaled)
  _Float16* kh     = (_Float16*)(ws + 24 * MB);  // [B,H,T,D] = 8MB
  _Float16* vth    = (_Float16*)(ws + 32 * MB);  // [B,H,D,T] = 8MB
  _Float16* oh     = (_Float16*)(ws + 40 * MB);  // [B,T,C]   = 8MB

  cast_f16_kernel<<<2048, 256, 0, stream>>>(x, xh, 4194304);
  transp_cast_kernel<<<dim3(48, 16), 256, 0, stream>>>(Wqkv, wqkvt, 1024, 3072);
  transp_cast_kernel<<<dim3(16, 16), 256, 0, stream>>>(Wproj, wprojt, 1024, 1024);

  gemm_f16<1><<<dim3(24, 32), 256, 0, stream>>>(xh, wqkvt, bqkv, nullptr, qh, kh, vth,
                                                4096, 3072, 1024);
  attn_kernel<<<dim3(1024), 256, 0, stream>>>(qh, kh, vth, oh);
  gemm_f16<0><<<dim3(8, 32), 256, 0, stream>>>(oh, wprojt, bproj, out, nullptr, nullptr, nullptr,
                                               4096, 1024, 1024);
}

// Round 9
// 137.493 us; speedup vs baseline: 1.6337x; 1.0583x over previous
//
#include <hip/hip_runtime.h>

typedef __attribute__((ext_vector_type(8))) _Float16 h8;
typedef __attribute__((ext_vector_type(4))) _Float16 h4;
typedef __attribute__((ext_vector_type(2))) _Float16 h2;
typedef __attribute__((ext_vector_type(4))) float f4;
typedef __attribute__((ext_vector_type(16))) float f16v;

#define QKSCALE 0.18033688011112042f  // 2^-3 * log2(e): fold softmax scale + exp2 conversion into Q
#define Z16 {0.f,0.f,0.f,0.f,0.f,0.f,0.f,0.f,0.f,0.f,0.f,0.f,0.f,0.f,0.f,0.f}

// async global->LDS, 16B per lane (dest must be lane-linear; source may be per-lane swizzled)
__device__ __forceinline__ void gload16(const void* g, void* l) {
  __builtin_amdgcn_global_load_lds((const __attribute__((address_space(1))) void*)g,
                                   (__attribute__((address_space(3))) void*)l, 16, 0, 0);
}

__device__ __forceinline__ h2 pkh2(float a, float b) {
  return __builtin_bit_cast(h2, __builtin_amdgcn_cvt_pkrtz(a, b));
}
__device__ __forceinline__ h2 swap32_h2(h2 v) {
  return __builtin_bit_cast(h2, __shfl_xor(__builtin_bit_cast(int, v), 32));
}

// ---------------- cast x (fp32 -> f16) ----------------
__global__ __launch_bounds__(256) void cast_f16_kernel(const float* __restrict__ in,
                                                       _Float16* __restrict__ out, int n) {
  int i = (blockIdx.x * 256 + threadIdx.x) * 8;
  if (i >= n) return;
  const float4* p = (const float4*)(in + i);
  float4 a = p[0], b = p[1];
  h8 v;
  v[0] = (_Float16)a.x; v[1] = (_Float16)a.y; v[2] = (_Float16)a.z; v[3] = (_Float16)a.w;
  v[4] = (_Float16)b.x; v[5] = (_Float16)b.y; v[6] = (_Float16)b.z; v[7] = (_Float16)b.w;
  *(h8*)(out + i) = v;
}

// ---------------- transpose-cast W [K][N] fp32 -> Wt [N][K] f16 ----------------
__global__ __launch_bounds__(256) void transp_cast_kernel(const float* __restrict__ W,
                                                          _Float16* __restrict__ Wt, int K, int N) {
  __shared__ _Float16 tile[64][72];
  int k0 = blockIdx.y * 64, n0 = blockIdx.x * 64;
  int t = threadIdx.x;
#pragma unroll
  for (int i = 0; i < 16; ++i) {
    int idx = i * 256 + t;
    int kr = idx >> 6, nc = idx & 63;
    tile[kr][nc] = (_Float16)W[(size_t)(k0 + kr) * N + n0 + nc];
  }
  __syncthreads();
#pragma unroll
  for (int i = 0; i < 2; ++i) {
    int idx = i * 256 + t;
    int nr = idx >> 3, kc = (idx & 7) * 8;
    h8 v;
#pragma unroll
    for (int j = 0; j < 8; ++j) v[j] = tile[kc + j][nr];
    *(h8*)&Wt[(size_t)(n0 + nr) * K + k0 + kc] = v;
  }
}

// ---------------- GEMM: C[M,N] = A[M,K] * Bt[N,K]^T (+bias), f16 MFMA ----------------
// Staging via global_load_lds width=16 (m97 pattern): LDS dest lane-linear,
// XOR chunk swizzle applied to the SOURCE address; reads XOR the chunk index.
// MODE 0: outF fp32 row-major.  MODE 1: QKV scatter -> Q[B,H,T,D]*QKSCALE, K[B,H,T,D], V^T[B,H,D,T]
template <int MODE>
__global__ __launch_bounds__(256) void gemm_f16(const _Float16* __restrict__ A,
                                                const _Float16* __restrict__ Bt,
                                                const float* __restrict__ bias,
                                                float* __restrict__ outF,
                                                _Float16* __restrict__ oQ,
                                                _Float16* __restrict__ oK,
                                                _Float16* __restrict__ oV,
                                                int M, int N, int K) {
  __shared__ _Float16 As[128 * 64];
  __shared__ _Float16 Bs[128 * 64];
  const int m0 = blockIdx.y * 128, n0 = blockIdx.x * 128;
  const int tid = threadIdx.x;
  const int wave = tid >> 6, lane = tid & 63;
  const int wr = (wave >> 1) * 64, wc = (wave & 1) * 64;
  const int lrow = lane & 15, g = lane >> 4;

  const int row_ = tid >> 3, c_ = tid & 7;

  f4 acc[4][4];
  const f4 z4 = {0.f, 0.f, 0.f, 0.f};
#pragma unroll
  for (int m = 0; m < 4; ++m)
#pragma unroll
    for (int n = 0; n < 4; ++n) acc[m][n] = z4;

  for (int k0 = 0; k0 < K; k0 += 64) {
#pragma unroll
    for (int i = 0; i < 4; ++i) {
      int row = i * 32 + row_;
      int cs = (c_ ^ (row & 7)) * 8;
      int ldst = (i * 256 + tid) * 8;
      gload16(&A[(size_t)(m0 + row) * K + k0 + cs], &As[ldst]);
      gload16(&Bt[(size_t)(n0 + row) * K + k0 + cs], &Bs[ldst]);
    }
    __syncthreads();
#pragma unroll
    for (int ss = 0; ss < 2; ++ss) {
      h8 af[4], bf[4];
#pragma unroll
      for (int m = 0; m < 4; ++m) {
        int row = wr + m * 16 + lrow;
        af[m] = *(const h8*)&As[row * 64 + (((ss * 4 + g) ^ (row & 7)) * 8)];
      }
#pragma unroll
      for (int n = 0; n < 4; ++n) {
        int row = wc + n * 16 + lrow;
        bf[n] = *(const h8*)&Bs[row * 64 + (((ss * 4 + g) ^ (row & 7)) * 8)];
      }
      __builtin_amdgcn_s_setprio(1);
#pragma unroll
      for (int m = 0; m < 4; ++m)
#pragma unroll
        for (int n = 0; n < 4; ++n)
          acc[m][n] = __builtin_amdgcn_mfma_f32_16x16x32_f16(af[m], bf[n], acc[m][n], 0, 0, 0);
      __builtin_amdgcn_s_setprio(0);
    }
    __syncthreads();
  }

  // epilogue; C/D layout: col = lane&15, row = (lane>>4)*4 + r  [m89]
#pragma unroll
  for (int n = 0; n < 4; ++n) {
    const int gcol = n0 + wc + n * 16 + lrow;
    const float bv = bias ? bias[gcol] : 0.f;
    if (MODE == 1 && (gcol >> 10) == 2) {
      const int c1 = gcol & 1023;
      const int hh = c1 >> 6, d = c1 & 63;
#pragma unroll
      for (int m = 0; m < 4; ++m) {
        const int grow = m0 + wr + m * 16 + g * 4;
        const int b = grow >> 11, t = grow & 2047;
        h4 pv;
#pragma unroll
        for (int r = 0; r < 4; ++r) pv[r] = (_Float16)(acc[m][n][r] + bv);
        *(h4*)&oV[(((size_t)(b * 16 + hh)) * 64 + d) * 2048 + t] = pv;
      }
    } else {
#pragma unroll
      for (int m = 0; m < 4; ++m) {
#pragma unroll
        for (int r = 0; r < 4; ++r) {
          const int grow = m0 + wr + m * 16 + g * 4 + r;
          float v = acc[m][n][r] + bv;
          if (MODE == 0) {
            outF[(size_t)grow * N + gcol] = v;
          } else {
            int part = gcol >> 10;
            int c1 = gcol & 1023;
            int hh = c1 >> 6, d = c1 & 63;
            int b = grow >> 11, t = grow & 2047;
            int bh = b * 16 + hh;
            if (part == 0)
              oQ[((size_t)bh * 2048 + t) * 64 + d] = (_Float16)(v * QKSCALE);
            else
              oK[((size_t)bh * 2048 + t) * 64 + d] = (_Float16)v;
          }
        }
      }
    }
  }
}

// ---------------- flash attention v9: block-cooperative LDS-staged K/V ----------------
// r8 showed 2x TLP bought only 4% -> vmem gather path is the serialized resource
// (8 gather instrs x ~32 lines each per wave-iteration). v9 stages 4 KV tiles per
// super-iteration cooperatively: K via global_load_lds (16KB contiguous, source-XOR
// chunk swizzle = GEMM pattern), V via reg->LDS (T14) into padded [64][136] rows.
// Wave w computes tile 4s+w from LDS. 4x fewer vmem instructions + line-touches.
// Compute core (swapped S^T=K.Q^T 32x32, in-reg softmax, cvt_pkrtz+swap32 P) = v8.
// slab for the merge ALIASES the K/V staging LDS (dead by then; barriers protect).
__global__ __launch_bounds__(256) void attn_kernel(const _Float16* __restrict__ Qg,
                                                   const _Float16* __restrict__ Kg,
                                                   const _Float16* __restrict__ Vtg,
                                                   _Float16* __restrict__ Og) {
  __shared__ __align__(16) char smem[33792];  // K 16384 + V 17408
  __shared__ float mlds[2][4][32];            // [0]=m, [1]=l per wave per q-row
  _Float16* Kb = (_Float16*)smem;                            // [4][32][64] flat
  _Float16(*Vb)[136] = (_Float16(*)[136])(smem + 16384);     // [64][136] padded
  _Float16(*slab)[32][72] = (_Float16(*)[32][72])smem;       // [4][32][72] alias (merge phase)

  const int idx = blockIdx.x;  // 0..1023
  const int bh = (idx & 7) | (((idx >> 3) & 3) << 3);
  const int pi = idx >> 5;  // 0..31: q-tiles (63-pi) and (pi)

  const int tid = threadIdx.x;
  const int wave = tid >> 6, lane = tid & 63;
  const int ln = lane & 31, hi = lane >> 5;
  const int b = bh >> 4, h = bh & 15;
  const _Float16* Q = Qg + (size_t)bh * 2048 * 64;
  const _Float16* K = Kg + (size_t)bh * 2048 * 64;
  const _Float16* Vt = Vtg + (size_t)bh * 64 * 2048;

  for (int half = 0; half < 2; ++half) {
    const int qt2 = half == 0 ? 63 - pi : pi;
    const int q0 = qt2 * 32;

    // Q^T B-frags: col q=ln, k-elems d = ds*16 + hi*8 + j
    h8 qf[4];
#pragma unroll
    for (int ds = 0; ds < 4; ++ds)
      qf[ds] = *(const h8*)&Q[(q0 + ln) * 64 + ds * 16 + hi * 8];

    f16v o0 = Z16, o1 = Z16;
    float m = -1e30f, l = 0.f;
    const int NT = qt2 + 1;        // KV tiles of 32 covering kv in [0, q0+32)
    const int S = (NT + 3) >> 2;   // super-iterations (4 tiles each)

    for (int s = 0; s < S; ++s) {
      const int kvs = s * 128;
      // ---- stage K: 16KB contiguous, gload_lds, source-XOR chunk swizzle ----
#pragma unroll
      for (int i = 0; i < 4; ++i) {
        const int L = i * 256 + tid;
        const int row = L >> 3, c = L & 7;
        const int cs = (c ^ (row & 7)) * 8;
        gload16(&K[(size_t)(kvs + row) * 64 + cs], &Kb[L * 8]);
      }
      // ---- stage V: reg -> LDS (T14 split), padded rows kill bank conflicts ----
      h8 vt[4];
#pragma unroll
      for (int i = 0; i < 4; ++i) {
        const int J = i * 256 + tid;
        const int d = J >> 4, ch = J & 15;
        vt[i] = *(const h8*)&Vt[(size_t)d * 2048 + kvs + ch * 8];
      }
#pragma unroll
      for (int i = 0; i < 4; ++i) {
        const int J = i * 256 + tid;
        const int d = J >> 4, ch = J & 15;
        *(h8*)&Vb[d][ch * 8] = vt[i];
      }
      __syncthreads();  // drains vmcnt (gload_lds) + lgkm -> tiles ready

      const int tI = s * 4 + wave;  // this wave's tile
      if (tI < NT) {
        const int kvloc = wave * 32;  // column base within staged V

        // K A-frags from LDS (XOR chunk read-back)
        h8 kf[4];
#pragma unroll
        for (int ds = 0; ds < 4; ++ds)
          kf[ds] = *(const h8*)&Kb[wave * 2048 + ln * 64 + (((ds * 2 + hi) ^ (ln & 7)) * 8)];

        f16v sv = Z16;
        __builtin_amdgcn_s_setprio(1);
#pragma unroll
        for (int ds = 0; ds < 4; ++ds)
          sv = __builtin_amdgcn_mfma_f32_32x32x16_f16(kf[ds], qf[ds], sv, 0, 0, 0);
        __builtin_amdgcn_s_setprio(0);

        if (tI == NT - 1) {  // diagonal tile (kv0 == q0): mask kk=crow > q=ln
#pragma unroll
          for (int reg = 0; reg < 16; ++reg) {
            const int crow = (reg & 3) + 8 * (reg >> 2) + 4 * hi;
            if (crow > ln) sv[reg] = -1e30f;
          }
        }

        // in-lane row max + one cross-half exchange
        float pm = sv[0];
#pragma unroll
        for (int reg = 1; reg < 16; ++reg) pm = fmaxf(pm, sv[reg]);
        pm = fmaxf(pm, __shfl_xor(pm, 32));

        if (__any(pm > m + 8.f)) {  // defer-max slow path
          const float mn = fmaxf(m, pm);
          const float fr = __builtin_amdgcn_exp2f(m - mn);
          m = mn;
          l *= fr;
#pragma unroll
          for (int reg = 0; reg < 16; ++reg) {
            const float frr = __shfl(fr, (reg & 3) + 8 * (reg >> 2) + 4 * hi);
            o0[reg] *= frr;
            o1[reg] *= frr;
          }
        }

        // exp (lane-local m) + lane-partial l
        float ls = 0.f;
#pragma unroll
        for (int reg = 0; reg < 16; ++reg) {
          sv[reg] = __builtin_amdgcn_exp2f(sv[reg] - m);
          ls += sv[reg];
        }
        l += ls;

        // pack P pairs
        h2 Pk[4][2];
#pragma unroll
        for (int R = 0; R < 4; ++R)
#pragma unroll
          for (int pr = 0; pr < 2; ++pr)
            Pk[R][pr] = pkh2(sv[4 * R + 2 * pr], sv[4 * R + 2 * pr + 1]);

        // assemble PV A-frags + accumulate; V B-frags from LDS
        __builtin_amdgcn_s_setprio(1);
#pragma unroll
        for (int ks = 0; ks < 2; ++ks) {
          const int Rb = 2 * ks;
          h2 a0p0 = Pk[Rb][0], a0p1 = Pk[Rb][1];
          h2 a1p0 = Pk[Rb + 1][0], a1p1 = Pk[Rb + 1][1];
          h2 loc0 = hi ? a1p0 : a0p0;
          h2 loc1 = hi ? a1p1 : a0p1;
          h2 snd0 = hi ? a0p0 : a1p0;
          h2 snd1 = hi ? a0p1 : a1p1;
          h2 rem0 = swap32_h2(snd0);
          h2 rem1 = swap32_h2(snd1);
          h2 w0 = hi ? rem0 : loc0;
          h2 w1 = hi ? rem1 : loc1;
          h2 w2 = hi ? loc0 : rem0;
          h2 w3 = hi ? loc1 : rem1;
          h8 pa;
          pa[0] = w0[0]; pa[1] = w0[1]; pa[2] = w1[0]; pa[3] = w1[1];
          pa[4] = w2[0]; pa[5] = w2[1]; pa[6] = w3[0]; pa[7] = w3[1];
          h8 vf0 = *(const h8*)&Vb[ln][kvloc + ks * 16 + hi * 8];
          h8 vf1 = *(const h8*)&Vb[32 + ln][kvloc + ks * 16 + hi * 8];
          o0 = __builtin_amdgcn_mfma_f32_32x32x16_f16(pa, vf0, o0, 0, 0, 0);
          o1 = __builtin_amdgcn_mfma_f32_32x32x16_f16(pa, vf1, o1, 0, 0, 0);
        }
        __builtin_amdgcn_s_setprio(0);
      }
      __syncthreads();  // protect Kb/Vb for next stage (and slab after loop)
    }

    // ---- finalize l; write per-wave partials (normalized f16 O + m,l) ----
    const float l_all = l + __shfl_xor(l, 32);
    if (hi == 0) {
      mlds[0][wave][ln] = m;
      mlds[1][wave][ln] = l_all;
    }
    _Float16(*pw)[72] = slab[wave];
#pragma unroll
    for (int reg = 0; reg < 16; ++reg) {
      const int crow = (reg & 3) + 8 * (reg >> 2) + 4 * hi;
      const float li = __shfl(l_all, crow);
      const float inv = li > 0.f ? 1.f / li : 0.f;
      pw[crow][ln] = (_Float16)(o0[reg] * inv);
      pw[crow][32 + ln] = (_Float16)(o1[reg] * inv);
    }
    __syncthreads();

    // ---- merge 4 waves & write O (f16 [B,T,C]); weights f_w = exp2(m_w - M) * l_w ----
    {
      const int ql = tid >> 3;          // 0..31
      const int d0 = (tid & 7) * 8;     // 0..56
      float m0 = mlds[0][0][ql], m1 = mlds[0][1][ql], m2 = mlds[0][2][ql], m3 = mlds[0][3][ql];
      float M = fmaxf(fmaxf(m0, m1), fmaxf(m2, m3));
      float f0 = __builtin_amdgcn_exp2f(m0 - M) * mlds[1][0][ql];
      float f1 = __builtin_amdgcn_exp2f(m1 - M) * mlds[1][1][ql];
      float f2 = __builtin_amdgcn_exp2f(m2 - M) * mlds[1][2][ql];
      float f3 = __builtin_amdgcn_exp2f(m3 - M) * mlds[1][3][ql];
      float inv = 1.f / (f0 + f1 + f2 + f3);
      h8 o0v = *(const h8*)&slab[0][ql][d0];
      h8 o1v = *(const h8*)&slab[1][ql][d0];
      h8 o2v = *(const h8*)&slab[2][ql][d0];
      h8 o3v = *(const h8*)&slab[3][ql][d0];
      h8 outv;
#pragma unroll
      for (int j = 0; j < 8; ++j) {
        float v = f0 * (float)o0v[j] + f1 * (float)o1v[j] + f2 * (float)o2v[j] + f3 * (float)o3v[j];
        outv[j] = (_Float16)(v * inv);
      }
      *(h8*)&Og[((size_t)b * 2048 + q0 + ql) * 1024 + h * 64 + d0] = outv;
    }
    if (half == 0) __syncthreads();  // merge reads done before next half's staging
  }
}

// ---------------- launch ----------------
extern "C" void kernel_launch(void* const* d_in, const int* in_sizes, int n_in,
                              void* d_out, int out_size, void* d_ws, size_t ws_size,
                              hipStream_t stream) {
  const float* x = (const float*)d_in[0];       // [2,2048,1024]
  const float* Wqkv = (const float*)d_in[1];    // [1024,3072]
  const float* bqkv = (const float*)d_in[2];    // [3072]
  const float* Wproj = (const float*)d_in[3];   // [1024,1024]
  const float* bproj = (const float*)d_in[4];   // [1024]
  float* out = (float*)d_out;                   // [2,2048,1024] fp32

  char* ws = (char*)d_ws;
  const size_t MB = 1u << 20;
  _Float16* xh     = (_Float16*)(ws + 0 * MB);   // 4M f16 = 8MB
  _Float16* wqkvt  = (_Float16*)(ws + 8 * MB);   // [3072][1024] = 6MB
  _Float16* wprojt = (_Float16*)(ws + 14 * MB);  // [1024][1024] = 2MB
  _Float16* qh     = (_Float16*)(ws + 16 * MB);  // [B,H,T,D] = 8MB (pre-scaled)
  _Float16* kh     = (_Float16*)(ws + 24 * MB);  // [B,H,T,D] = 8MB
  _Float16* vth    = (_Float16*)(ws + 32 * MB);  // [B,H,D,T] = 8MB
  _Float16* oh     = (_Float16*)(ws + 40 * MB);  // [B,T,C]   = 8MB

  cast_f16_kernel<<<2048, 256, 0, stream>>>(x, xh, 4194304);
  transp_cast_kernel<<<dim3(48, 16), 256, 0, stream>>>(Wqkv, wqkvt, 1024, 3072);
  transp_cast_kernel<<<dim3(16, 16), 256, 0, stream>>>(Wproj, wprojt, 1024, 1024);

  gemm_f16<1><<<dim3(24, 32), 256, 0, stream>>>(xh, wqkvt, bqkv, nullptr, qh, kh, vth,
                                                4096, 3072, 1024);
  attn_kernel<<<dim3(1024), 256, 0, stream>>>(qh, kh, vth, oh);
  gemm_f16<0><<<dim3(8, 32), 256, 0, stream>>>(oh, wprojt, bproj, out, nullptr, nullptr, nullptr,
                                               4096, 1024, 1024);
}